// Round 1
// baseline (293.638 us; speedup 1.0000x reference)
//
#include <hip/hip_runtime.h>
#include <cstdint>

#define DEV __device__ __forceinline__

typedef __attribute__((ext_vector_type(4))) float f32x4;
typedef __attribute__((ext_vector_type(8))) short b16x8;
typedef __attribute__((ext_vector_type(4))) unsigned short u16x4;
typedef __attribute__((ext_vector_type(8))) unsigned short u16x8;

typedef __attribute__((address_space(1))) void gvoid_t;
typedef __attribute__((address_space(3))) void lvoid_t;

static constexpr int Bsz = 8, Ssz = 1024, Dsz = 1024;
static constexpr int Mrows = Bsz * Ssz;  // 8192

// async global->LDS, 16B per lane; lds base must be wave-uniform (HW adds lane*16)
DEV void gld16(const void* g, void* l) {
  __builtin_amdgcn_global_load_lds((gvoid_t*)(uintptr_t)g,
                                   (lvoid_t*)(unsigned)(uintptr_t)l, 16, 0, 0);
}

// fp32 -> bf16 RNE (finite inputs only)
DEV unsigned short f2bf(float x) {
  unsigned int u = __float_as_uint(x);
  u += 0x7fffu + ((u >> 16) & 1u);
  return (unsigned short)(u >> 16);
}

// ---------------------------------------------------------------------------
// Kernel 1: convert+transpose 4 weight matrices: Wt[w][n][k] = bf16(W[k][n])
// ---------------------------------------------------------------------------
__global__ __launch_bounds__(256) void wconv_kernel(
    const float* __restrict__ WQ, const float* __restrict__ WK,
    const float* __restrict__ WV, const float* __restrict__ WO,
    unsigned short* __restrict__ Wt) {
  __shared__ float tile[64][65];
  const int w = blockIdx.z;
  const float* W = (w == 0) ? WQ : (w == 1) ? WK : (w == 2) ? WV : WO;
  const int k0 = blockIdx.x * 64, n0 = blockIdx.y * 64;
  const int t = threadIdx.x;
  {
    const int r = t >> 4;
    const int c = (t & 15) * 4;
#pragma unroll
    for (int i = 0; i < 4; ++i) {
      f32x4 v = *(const f32x4*)(W + (size_t)(k0 + i * 16 + r) * Dsz + n0 + c);
      tile[i * 16 + r][c + 0] = v[0];
      tile[i * 16 + r][c + 1] = v[1];
      tile[i * 16 + r][c + 2] = v[2];
      tile[i * 16 + r][c + 3] = v[3];
    }
  }
  __syncthreads();
  {
    const int n = t >> 2;
    const int ks = (t & 3) * 16;
    unsigned short* dst =
        Wt + (size_t)w * Dsz * Dsz + (size_t)(n0 + n) * Dsz + k0 + ks;
#pragma unroll
    for (int j = 0; j < 16; j += 4) {
      u16x4 p;
#pragma unroll
      for (int jj = 0; jj < 4; ++jj) p[jj] = f2bf(tile[ks + j + jj][n]);
      *(u16x4*)(dst + j) = p;
    }
  }
}

// ---------------------------------------------------------------------------
// Kernel 2: 128x128-tile bf16 MFMA GEMM, C = relu(A @ Wt^T + bias)
//   A: [M][1024] fp32 (reg-staged+converted) or bf16 (global_load_lds)
//   Bt: [N][K] bf16 (weights pre-transposed) -> both operands k-contiguous
// ---------------------------------------------------------------------------
template <bool A_BF16, bool OUT_BF16>
DEV void gemm_body(const void* __restrict__ A_,
                   const unsigned short* __restrict__ Bt,
                   const float* __restrict__ bias, void* __restrict__ C_,
                   int m0, int n0) {
  constexpr int Kd = 1024, Nd = 1024;
  __shared__ unsigned short Asl[128 * 64] __attribute__((aligned(16)));
  __shared__ unsigned short Bsl[128 * 64] __attribute__((aligned(16)));
  const int t = threadIdx.x, lane = t & 63, wave = t >> 6;
  const int grp = lane >> 4, r16 = lane & 15;
  const int wm = wave >> 1, wn = wave & 1;
  f32x4 acc[4][4] = {};
  for (int kt = 0; kt < Kd; kt += 64) {
    // stage B tile [128 n][64 k] bf16 = 16KB via async 16B direct-to-LDS
#pragma unroll
    for (int j = 0; j < 4; ++j) {
      int chunk = (wave * 4 + j) * 64 + lane;
      int row = chunk >> 3, c = chunk & 7;
      gld16(Bt + (size_t)(n0 + row) * Kd + kt + c * 8,
            (char*)Bsl + (wave * 4 + j) * 1024);
    }
    if constexpr (A_BF16) {
      const unsigned short* A = (const unsigned short*)A_;
#pragma unroll
      for (int j = 0; j < 4; ++j) {
        int chunk = (wave * 4 + j) * 64 + lane;
        int row = chunk >> 3, c = chunk & 7;
        gld16(A + (size_t)(m0 + row) * Kd + kt + c * 8,
              (char*)Asl + (wave * 4 + j) * 1024);
      }
    } else {
      const float* A = (const float*)A_;
#pragma unroll
      for (int it = 0; it < 4; ++it) {
        int chunk = it * 256 + t;
        int row = chunk >> 3, c = chunk & 7;
        const float* src = A + (size_t)(m0 + row) * Kd + kt + c * 8;
        f32x4 v0 = *(const f32x4*)src;
        f32x4 v1 = *(const f32x4*)(src + 4);
        u16x8 p;
        p[0] = f2bf(v0[0]); p[1] = f2bf(v0[1]);
        p[2] = f2bf(v0[2]); p[3] = f2bf(v0[3]);
        p[4] = f2bf(v1[0]); p[5] = f2bf(v1[1]);
        p[6] = f2bf(v1[2]); p[7] = f2bf(v1[3]);
        *(u16x8*)((char*)Asl + chunk * 16) = p;  // contiguous ds_write_b128
      }
    }
    __syncthreads();
#pragma unroll
    for (int cs = 0; cs < 2; ++cs) {
      b16x8 af[4], bfr[4];
#pragma unroll
      for (int mi = 0; mi < 4; ++mi)
        af[mi] = *(const b16x8*)((char*)Asl + (wm * 64 + mi * 16 + r16) * 128 +
                                 cs * 64 + grp * 16);
#pragma unroll
      for (int ni = 0; ni < 4; ++ni)
        bfr[ni] = *(const b16x8*)((char*)Bsl + (wn * 64 + ni * 16 + r16) * 128 +
                                  cs * 64 + grp * 16);
#pragma unroll
      for (int mi = 0; mi < 4; ++mi)
#pragma unroll
        for (int ni = 0; ni < 4; ++ni)
          acc[mi][ni] = __builtin_amdgcn_mfma_f32_16x16x32_bf16(
              af[mi], bfr[ni], acc[mi][ni], 0, 0, 0);
    }
    __syncthreads();
  }
  // epilogue: bias + relu; C/D layout: col=lane&15, row=(lane>>4)*4+r
#pragma unroll
  for (int mi = 0; mi < 4; ++mi) {
#pragma unroll
    for (int ni = 0; ni < 4; ++ni) {
      int col = n0 + wn * 64 + ni * 16 + r16;
      float bv = bias[col];
#pragma unroll
      for (int r = 0; r < 4; ++r) {
        int row = m0 + wm * 64 + mi * 16 + grp * 4 + r;
        float v = fmaxf(acc[mi][ni][r] + bv, 0.0f);
        if constexpr (OUT_BF16)
          ((unsigned short*)C_)[(size_t)row * Nd + col] = f2bf(v);
        else
          ((float*)C_)[(size_t)row * Nd + col] = v;
      }
    }
  }
}

__global__ __launch_bounds__(256) void proj_gemm_kernel(
    const float* __restrict__ Q, const float* __restrict__ K,
    const float* __restrict__ V, const unsigned short* __restrict__ Wt,
    const float* __restrict__ bQ, const float* __restrict__ bK,
    const float* __restrict__ bV, unsigned short* __restrict__ P) {
  const int z = blockIdx.z;
  const float* A = (z == 0) ? Q : (z == 1) ? K : V;
  const float* bias = (z == 0) ? bQ : (z == 1) ? bK : bV;
  gemm_body<false, true>(A, Wt + (size_t)z * Dsz * Dsz, bias,
                         P + (size_t)z * Mrows * Dsz, blockIdx.y * 128,
                         blockIdx.x * 128);
}

__global__ __launch_bounds__(256) void out_gemm_kernel(
    const unsigned short* __restrict__ AO,
    const unsigned short* __restrict__ WOt, const float* __restrict__ bO,
    float* __restrict__ Out) {
  gemm_body<true, false>(AO, WOt, bO, Out, blockIdx.y * 128, blockIdx.x * 128);
}

// ---------------------------------------------------------------------------
// Kernel 3: per-batch transpose Vp (B,S,D) -> VpT (B,D,S), bf16
// ---------------------------------------------------------------------------
__global__ __launch_bounds__(256) void vtrans_kernel(
    const unsigned short* __restrict__ Vp, unsigned short* __restrict__ VpT) {
  __shared__ unsigned short tile[64 * 67];
  const int b = blockIdx.z;
  const int s0 = blockIdx.x * 64, d0 = blockIdx.y * 64;
  const int t = threadIdx.x;
  {
    const int rr = t >> 4;
    const int c = (t & 15) * 4;
#pragma unroll
    for (int i = 0; i < 4; ++i) {
      int s = i * 16 + rr;
      u16x4 v = *(const u16x4*)(Vp + ((size_t)b * Ssz + s0 + s) * Dsz + d0 + c);
      tile[s * 67 + c + 0] = v[0];
      tile[s * 67 + c + 1] = v[1];
      tile[s * 67 + c + 2] = v[2];
      tile[s * 67 + c + 3] = v[3];
    }
  }
  __syncthreads();
  {
    const int d = t >> 2;
    const int sq = (t & 3) * 16;
    unsigned short* dst =
        VpT + ((size_t)b * Dsz + d0 + d) * Ssz + s0 + sq;
#pragma unroll
    for (int j = 0; j < 16; j += 4) {
      u16x4 p;
#pragma unroll
      for (int jj = 0; jj < 4; ++jj) p[jj] = tile[(sq + j + jj) * 67 + d];
      *(u16x4*)(dst + j) = p;
    }
  }
}

// ---------------------------------------------------------------------------
// Kernel 4: flash attention. Block = 4 waves, 64 Q-rows; per (b,head);
// KV-block 64; online softmax; K/V/P in XOR-swizzled LDS.
// Scores scaled by 1/sqrt(D)=1/32. Masks skipped (no zero rows post-ReLU).
// ---------------------------------------------------------------------------
__global__ __launch_bounds__(256) void attn_kernel(
    const unsigned short* __restrict__ Qp, const unsigned short* __restrict__ Kp,
    const unsigned short* __restrict__ VpT, unsigned short* __restrict__ AO) {
  __shared__ unsigned short Ks[64 * 64] __attribute__((aligned(16)));
  __shared__ unsigned short Vs[64 * 64] __attribute__((aligned(16)));
  __shared__ unsigned short Ps[4 * 16 * 64] __attribute__((aligned(16)));
  const int t = threadIdx.x, lane = t & 63, wave = t >> 6;
  const int grp = lane >> 4, r16 = lane & 15;
  const int bh = blockIdx.y;
  const int b = bh & 7, head = bh >> 3;
  const int q0 = blockIdx.x * 64;

  // Q fragments in registers (A-layout: row=lane&15, k=8*(lane>>4)+j)
  const int sq = q0 + wave * 16 + r16;
  const unsigned short* qbase = Qp + ((size_t)b * Ssz + sq) * Dsz + head * 64;
  b16x8 qf0 = *(const b16x8*)(qbase + grp * 8);
  b16x8 qf1 = *(const b16x8*)(qbase + 32 + grp * 8);

  f32x4 o[4] = {};
  float m_r[4], l_r[4];
#pragma unroll
  for (int r = 0; r < 4; ++r) { m_r[r] = -1e30f; l_r[r] = 0.0f; }
  const float scale = 0.03125f;  // 1/sqrt(1024)
  const float LOG2E = 1.4426950408889634f;
  const f32x4 zero4 = {0.0f, 0.0f, 0.0f, 0.0f};

  for (int kv0 = 0; kv0 < Ssz; kv0 += 64) {
    // stage K[64 k][64 d] and Vt[64 d][64 k]; source pre-swizzled so that
    // LDS chunk (row, c) holds global chunk (row, c ^ (row&7))
#pragma unroll
    for (int j = 0; j < 2; ++j) {
      int chunk = (wave * 2 + j) * 64 + lane;
      int row = chunk >> 3, c = chunk & 7;
      int csw = c ^ (row & 7);
      gld16(Kp + ((size_t)b * Ssz + kv0 + row) * Dsz + head * 64 + csw * 8,
            (char*)Ks + (wave * 2 + j) * 1024);
      gld16(VpT + ((size_t)b * Dsz + head * 64 + row) * Ssz + kv0 + csw * 8,
            (char*)Vs + (wave * 2 + j) * 1024);
    }
    __syncthreads();

    // S = Q K^T : sc[f] covers k-cols f*16..f*16+15 (col=lane&15 within frag)
    f32x4 sc[4];
#pragma unroll
    for (int f = 0; f < 4; ++f) {
      int k = f * 16 + r16;
      int swz = (k & 7) << 4;
      b16x8 kf0 = *(const b16x8*)((char*)Ks + k * 128 + ((grp * 16) ^ swz));
      b16x8 kf1 = *(const b16x8*)((char*)Ks + k * 128 + ((64 + grp * 16) ^ swz));
      f32x4 s = __builtin_amdgcn_mfma_f32_16x16x32_bf16(qf0, kf0, zero4, 0, 0, 0);
      sc[f] = __builtin_amdgcn_mfma_f32_16x16x32_bf16(qf1, kf1, s, 0, 0, 0);
    }

    // online softmax per q-row (row = grp*4+r); reduce across the 16 lanes
    // of the group (they hold k = r16 + 16f)
    float corr[4];
#pragma unroll
    for (int r = 0; r < 4; ++r) {
      float s0v = sc[0][r] * scale, s1v = sc[1][r] * scale;
      float s2v = sc[2][r] * scale, s3v = sc[3][r] * scale;
      float mx = fmaxf(fmaxf(s0v, s1v), fmaxf(s2v, s3v));
#pragma unroll
      for (int off = 8; off; off >>= 1) mx = fmaxf(mx, __shfl_xor(mx, off));
      float mnew = fmaxf(m_r[r], mx);
      float c_ = exp2f((m_r[r] - mnew) * LOG2E);
      float p0 = exp2f((s0v - mnew) * LOG2E);
      float p1 = exp2f((s1v - mnew) * LOG2E);
      float p2 = exp2f((s2v - mnew) * LOG2E);
      float p3 = exp2f((s3v - mnew) * LOG2E);
      float sum = p0 + p1 + p2 + p3;
#pragma unroll
      for (int off = 8; off; off >>= 1) sum += __shfl_xor(sum, off);
      l_r[r] = l_r[r] * c_ + sum;
      m_r[r] = mnew;
      corr[r] = c_;
      // store P row q=grp*4+r into per-wave LDS (swizzled like K/V)
      int q = grp * 4 + r;
      char* prow = (char*)Ps + wave * 2048 + q * 128;
      int qs = (q & 7) << 4;
      *(unsigned short*)(prow + ((r16 * 2 + 0) ^ qs)) = f2bf(p0);
      *(unsigned short*)(prow + ((r16 * 2 + 32) ^ qs)) = f2bf(p1);
      *(unsigned short*)(prow + ((r16 * 2 + 64) ^ qs)) = f2bf(p2);
      *(unsigned short*)(prow + ((r16 * 2 + 96) ^ qs)) = f2bf(p3);
    }

    // rescale existing accumulator, then O += P V
#pragma unroll
    for (int fc = 0; fc < 4; ++fc)
#pragma unroll
      for (int r = 0; r < 4; ++r) o[fc][r] *= corr[r];
#pragma unroll
    for (int ks = 0; ks < 2; ++ks) {
      int pswz = (r16 & 7) << 4;
      b16x8 pa = *(const b16x8*)((char*)Ps + wave * 2048 + r16 * 128 +
                                 ((ks * 64 + grp * 16) ^ pswz));
#pragma unroll
      for (int fc = 0; fc < 4; ++fc) {
        int d = fc * 16 + r16;
        int vswz = (d & 7) << 4;
        b16x8 vb = *(const b16x8*)((char*)Vs + d * 128 +
                                   ((ks * 64 + grp * 16) ^ vswz));
        o[fc] = __builtin_amdgcn_mfma_f32_16x16x32_bf16(pa, vb, o[fc], 0, 0, 0);
      }
    }
    __syncthreads();
  }

  // O /= l ; write AO[b][s][head*64 + d] bf16
#pragma unroll
  for (int fc = 0; fc < 4; ++fc) {
    int col = head * 64 + fc * 16 + r16;
#pragma unroll
    for (int r = 0; r < 4; ++r) {
      int row = q0 + wave * 16 + grp * 4 + r;
      AO[((size_t)b * Ssz + row) * Dsz + col] = f2bf(o[fc][r] / l_r[r]);
    }
  }
}

// ---------------------------------------------------------------------------
extern "C" void kernel_launch(void* const* d_in, const int* in_sizes, int n_in,
                              void* d_out, int out_size, void* d_ws,
                              size_t ws_size, hipStream_t stream) {
  const float* Q = (const float*)d_in[0];
  const float* K = (const float*)d_in[1];
  const float* V = (const float*)d_in[2];
  const float* WQ = (const float*)d_in[3];
  const float* bQ = (const float*)d_in[4];
  const float* WK = (const float*)d_in[5];
  const float* bK = (const float*)d_in[6];
  const float* WV = (const float*)d_in[7];
  const float* bV = (const float*)d_in[8];
  const float* WO = (const float*)d_in[9];
  const float* bO = (const float*)d_in[10];

  char* ws = (char*)d_ws;
  const size_t MB = 1024ull * 1024ull;
  unsigned short* Wt = (unsigned short*)(ws);             // 8 MB: 4x[n][k] bf16
  unsigned short* Pp = (unsigned short*)(ws + 8 * MB);    // Qp,Kp,Vp: 48 MB
  unsigned short* Qp = Pp;
  unsigned short* Kp = Pp + (size_t)Mrows * Dsz;
  unsigned short* Vp = Pp + 2 * (size_t)Mrows * Dsz;
  unsigned short* VpT = (unsigned short*)(ws + 56 * MB);  // 16 MB
  unsigned short* AO = Vp;  // Vp dead after vtrans -> reuse as attention out

  wconv_kernel<<<dim3(16, 16, 4), 256, 0, stream>>>(WQ, WK, WV, WO, Wt);
  proj_gemm_kernel<<<dim3(8, 64, 3), 256, 0, stream>>>(Q, K, V, Wt, bQ, bK, bV,
                                                       Pp);
  vtrans_kernel<<<dim3(16, 16, 8), 256, 0, stream>>>(Vp, VpT);
  attn_kernel<<<dim3(16, 128), 256, 0, stream>>>(Qp, Kp, VpT, AO);
  out_gemm_kernel<<<dim3(8, 64), 256, 0, stream>>>(
      AO, Wt + 3 * (size_t)Dsz * Dsz, bO, (float*)d_out);
}

// Round 2
// 252.199 us; speedup vs baseline: 1.1643x; 1.1643x over previous
//
#include <hip/hip_runtime.h>
#include <cstdint>

#define DEV __device__ __forceinline__

typedef __attribute__((ext_vector_type(4))) float f32x4;
typedef __attribute__((ext_vector_type(8))) short b16x8;
typedef __attribute__((ext_vector_type(4))) unsigned short u16x4;
typedef __attribute__((ext_vector_type(8))) unsigned short u16x8;

typedef __attribute__((address_space(1))) void gvoid_t;
typedef __attribute__((address_space(3))) void lvoid_t;

static constexpr int Bsz = 8, Ssz = 1024, Dsz = 1024;
static constexpr int Mrows = Bsz * Ssz;  // 8192

// async global->LDS, 16B per lane; lds base must be wave-uniform (HW adds lane*16)
DEV void gld16(const void* g, void* l) {
  __builtin_amdgcn_global_load_lds((gvoid_t*)(uintptr_t)g,
                                   (lvoid_t*)(unsigned)(uintptr_t)l, 16, 0, 0);
}

// fp32 -> bf16 RNE (finite inputs only)
DEV unsigned short f2bf(float x) {
  unsigned int u = __float_as_uint(x);
  u += 0x7fffu + ((u >> 16) & 1u);
  return (unsigned short)(u >> 16);
}

// ---------------------------------------------------------------------------
// Kernel 1: convert+transpose 4 weight matrices: Wt[w][n][k] = bf16(W[k][n])
// ---------------------------------------------------------------------------
__global__ __launch_bounds__(256) void wconv_kernel(
    const float* __restrict__ WQ, const float* __restrict__ WK,
    const float* __restrict__ WV, const float* __restrict__ WO,
    unsigned short* __restrict__ Wt) {
  __shared__ float tile[64][65];
  const int w = blockIdx.z;
  const float* W = (w == 0) ? WQ : (w == 1) ? WK : (w == 2) ? WV : WO;
  const int k0 = blockIdx.x * 64, n0 = blockIdx.y * 64;
  const int t = threadIdx.x;
  {
    const int r = t >> 4;
    const int c = (t & 15) * 4;
#pragma unroll
    for (int i = 0; i < 4; ++i) {
      f32x4 v = *(const f32x4*)(W + (size_t)(k0 + i * 16 + r) * Dsz + n0 + c);
      tile[i * 16 + r][c + 0] = v[0];
      tile[i * 16 + r][c + 1] = v[1];
      tile[i * 16 + r][c + 2] = v[2];
      tile[i * 16 + r][c + 3] = v[3];
    }
  }
  __syncthreads();
  {
    const int n = t >> 2;
    const int ks = (t & 3) * 16;
    unsigned short* dst =
        Wt + (size_t)w * Dsz * Dsz + (size_t)(n0 + n) * Dsz + k0 + ks;
#pragma unroll
    for (int j = 0; j < 16; j += 4) {
      u16x4 p;
#pragma unroll
      for (int jj = 0; jj < 4; ++jj) p[jj] = f2bf(tile[ks + j + jj][n]);
      *(u16x4*)(dst + j) = p;
    }
  }
}

// ---------------------------------------------------------------------------
// Kernel 2: 128x128-tile bf16 MFMA GEMM, C = relu(A @ Wt^T + bias) * outscale
//   LDS XOR-swizzled (T2): slot (row,c) holds data (row, c^(row&7));
//   achieved by pre-swizzling the SOURCE address (gld16 dest must be linear).
// ---------------------------------------------------------------------------
template <bool A_BF16, bool OUT_BF16>
DEV void gemm_body(const void* __restrict__ A_,
                   const unsigned short* __restrict__ Bt,
                   const float* __restrict__ bias, void* __restrict__ C_,
                   int m0, int n0, float outscale) {
  constexpr int Kd = 1024, Nd = 1024;
  __shared__ unsigned short Asl[128 * 64] __attribute__((aligned(16)));
  __shared__ unsigned short Bsl[128 * 64] __attribute__((aligned(16)));
  const int t = threadIdx.x, lane = t & 63, wave = t >> 6;
  const int grp = lane >> 4, r16 = lane & 15;
  const int wm = wave >> 1, wn = wave & 1;
  const int swz = (r16 & 7) << 4;  // read-side XOR (row&7 == r16&7 here)
  f32x4 acc[4][4] = {};
  for (int kt = 0; kt < Kd; kt += 64) {
    // stage B tile [128 n][64 k] bf16 = 16KB, source pre-swizzled
#pragma unroll
    for (int j = 0; j < 4; ++j) {
      int chunk = (wave * 4 + j) * 64 + lane;
      int row = chunk >> 3, c = chunk & 7;
      int csw = c ^ (row & 7);
      gld16(Bt + (size_t)(n0 + row) * Kd + kt + csw * 8,
            (char*)Bsl + (wave * 4 + j) * 1024);
    }
    if constexpr (A_BF16) {
      const unsigned short* A = (const unsigned short*)A_;
#pragma unroll
      for (int j = 0; j < 4; ++j) {
        int chunk = (wave * 4 + j) * 64 + lane;
        int row = chunk >> 3, c = chunk & 7;
        int csw = c ^ (row & 7);
        gld16(A + (size_t)(m0 + row) * Kd + kt + csw * 8,
              (char*)Asl + (wave * 4 + j) * 1024);
      }
    } else {
      const float* A = (const float*)A_;
#pragma unroll
      for (int it = 0; it < 4; ++it) {
        int chunk = it * 256 + t;
        int row = chunk >> 3, c = chunk & 7;
        int csw = c ^ (row & 7);
        const float* src = A + (size_t)(m0 + row) * Kd + kt + csw * 8;
        f32x4 v0 = *(const f32x4*)src;
        f32x4 v1 = *(const f32x4*)(src + 4);
        u16x8 p;
        p[0] = f2bf(v0[0]); p[1] = f2bf(v0[1]);
        p[2] = f2bf(v0[2]); p[3] = f2bf(v0[3]);
        p[4] = f2bf(v1[0]); p[5] = f2bf(v1[1]);
        p[6] = f2bf(v1[2]); p[7] = f2bf(v1[3]);
        *(u16x8*)((char*)Asl + chunk * 16) = p;  // linear slot, swizzled data
      }
    }
    __syncthreads();
#pragma unroll
    for (int cs = 0; cs < 2; ++cs) {
      b16x8 af[4], bfr[4];
#pragma unroll
      for (int mi = 0; mi < 4; ++mi)
        af[mi] = *(const b16x8*)((char*)Asl + (wm * 64 + mi * 16 + r16) * 128 +
                                 ((cs * 64 + grp * 16) ^ swz));
#pragma unroll
      for (int ni = 0; ni < 4; ++ni)
        bfr[ni] = *(const b16x8*)((char*)Bsl + (wn * 64 + ni * 16 + r16) * 128 +
                                  ((cs * 64 + grp * 16) ^ swz));
#pragma unroll
      for (int mi = 0; mi < 4; ++mi)
#pragma unroll
        for (int ni = 0; ni < 4; ++ni)
          acc[mi][ni] = __builtin_amdgcn_mfma_f32_16x16x32_bf16(
              af[mi], bfr[ni], acc[mi][ni], 0, 0, 0);
    }
    __syncthreads();
  }
  // epilogue: bias + relu (+scale); C/D layout: col=lane&15, row=(lane>>4)*4+r
#pragma unroll
  for (int mi = 0; mi < 4; ++mi) {
#pragma unroll
    for (int ni = 0; ni < 4; ++ni) {
      int col = n0 + wn * 64 + ni * 16 + r16;
      float bv = bias[col];
#pragma unroll
      for (int r = 0; r < 4; ++r) {
        int row = m0 + wm * 64 + mi * 16 + grp * 4 + r;
        float v = fmaxf(acc[mi][ni][r] + bv, 0.0f) * outscale;
        if constexpr (OUT_BF16)
          ((unsigned short*)C_)[(size_t)row * Nd + col] = f2bf(v);
        else
          ((float*)C_)[(size_t)row * Nd + col] = v;
      }
    }
  }
}

// Q projection pre-scaled by 1/sqrt(D)*log2(e) so attention softmax runs in
// exp2 domain with no per-score scaling (relu commutes with positive scale).
static constexpr float QSCALE = 0.03125f * 1.4426950408889634f;

__global__ __launch_bounds__(256) void proj_gemm_kernel(
    const float* __restrict__ Q, const float* __restrict__ K,
    const float* __restrict__ V, const unsigned short* __restrict__ Wt,
    const float* __restrict__ bQ, const float* __restrict__ bK,
    const float* __restrict__ bV, unsigned short* __restrict__ P) {
  const int z = blockIdx.z;
  const float* A = (z == 0) ? Q : (z == 1) ? K : V;
  const float* bias = (z == 0) ? bQ : (z == 1) ? bK : bV;
  float outscale = (z == 0) ? QSCALE : 1.0f;
  gemm_body<false, true>(A, Wt + (size_t)z * Dsz * Dsz, bias,
                         P + (size_t)z * Mrows * Dsz, blockIdx.y * 128,
                         blockIdx.x * 128, outscale);
}

__global__ __launch_bounds__(256) void out_gemm_kernel(
    const unsigned short* __restrict__ AO,
    const unsigned short* __restrict__ WOt, const float* __restrict__ bO,
    float* __restrict__ Out) {
  gemm_body<true, false>(AO, WOt, bO, Out, blockIdx.y * 128, blockIdx.x * 128,
                         1.0f);
}

// ---------------------------------------------------------------------------
// Kernel 3: per-batch transpose Vp (B,S,D) -> VpT (B,D,S), bf16
// ---------------------------------------------------------------------------
__global__ __launch_bounds__(256) void vtrans_kernel(
    const unsigned short* __restrict__ Vp, unsigned short* __restrict__ VpT) {
  __shared__ unsigned short tile[64 * 67];
  const int b = blockIdx.z;
  const int s0 = blockIdx.x * 64, d0 = blockIdx.y * 64;
  const int t = threadIdx.x;
  {
    const int rr = t >> 4;
    const int c = (t & 15) * 4;
#pragma unroll
    for (int i = 0; i < 4; ++i) {
      int s = i * 16 + rr;
      u16x4 v = *(const u16x4*)(Vp + ((size_t)b * Ssz + s0 + s) * Dsz + d0 + c);
      tile[s * 67 + c + 0] = v[0];
      tile[s * 67 + c + 1] = v[1];
      tile[s * 67 + c + 2] = v[2];
      tile[s * 67 + c + 3] = v[3];
    }
  }
  __syncthreads();
  {
    const int d = t >> 2;
    const int sq = (t & 3) * 16;
    unsigned short* dst =
        VpT + ((size_t)b * Dsz + d0 + d) * Ssz + s0 + sq;
#pragma unroll
    for (int j = 0; j < 16; j += 4) {
      u16x4 p;
#pragma unroll
      for (int jj = 0; jj < 4; ++jj) p[jj] = tile[(sq + j + jj) * 67 + d];
      *(u16x4*)(dst + j) = p;
    }
  }
}

// ---------------------------------------------------------------------------
// Kernel 4: flash attention, swapped-QK^T form.
//   S^T = mfma(K, Q): lane holds q = lane&15 (one q-row!), k = f*16+grp*4+r.
//   -> softmax: 15 in-lane fmax + 2 shfl_xor; one m/l scalar per lane;
//      P packed as 4x ds_write_b64.
//   Qp comes pre-scaled by 1/sqrt(D)*log2e, so p = exp2(s - m) directly.
// ---------------------------------------------------------------------------
__global__ __launch_bounds__(256) void attn_kernel(
    const unsigned short* __restrict__ Qp, const unsigned short* __restrict__ Kp,
    const unsigned short* __restrict__ VpT, unsigned short* __restrict__ AO) {
  __shared__ unsigned short Ks[64 * 64] __attribute__((aligned(16)));
  __shared__ unsigned short Vs[64 * 64] __attribute__((aligned(16)));
  __shared__ unsigned short Ps[4 * 16 * 64] __attribute__((aligned(16)));
  const int t = threadIdx.x, lane = t & 63, wave = t >> 6;
  const int grp = lane >> 4, r16 = lane & 15;
  const int bh = blockIdx.y;
  const int b = bh & 7, head = bh >> 3;
  const int q0 = blockIdx.x * 64;

  // Q fragments (B-operand layout: row=lane&15 ↔ q, k = 8*grp + j)
  const int sq = q0 + wave * 16 + r16;
  const unsigned short* qbase = Qp + ((size_t)b * Ssz + sq) * Dsz + head * 64;
  b16x8 qf0 = *(const b16x8*)(qbase + grp * 8);
  b16x8 qf1 = *(const b16x8*)(qbase + 32 + grp * 8);

  f32x4 o[4] = {};
  float m2 = -1e30f, l = 0.0f;
  const f32x4 zero4 = {0.0f, 0.0f, 0.0f, 0.0f};

  for (int kv0 = 0; kv0 < Ssz; kv0 += 64) {
    // stage K[64 k][64 d] and Vt[64 d][64 k]; source pre-swizzled so that
    // LDS chunk (row, c) holds global chunk (row, c ^ (row&7))
#pragma unroll
    for (int j = 0; j < 2; ++j) {
      int chunk = (wave * 2 + j) * 64 + lane;
      int row = chunk >> 3, c = chunk & 7;
      int csw = c ^ (row & 7);
      gld16(Kp + ((size_t)b * Ssz + kv0 + row) * Dsz + head * 64 + csw * 8,
            (char*)Ks + (wave * 2 + j) * 1024);
      gld16(VpT + ((size_t)b * Dsz + head * 64 + row) * Ssz + kv0 + csw * 8,
            (char*)Vs + (wave * 2 + j) * 1024);
    }
    __syncthreads();

    // S^T = K Q^T : sc[f] rows = k = f*16 + grp*4 + r, col = q = r16
    f32x4 sc[4];
#pragma unroll
    for (int f = 0; f < 4; ++f) {
      int k = f * 16 + r16;
      int kswz = (k & 7) << 4;
      b16x8 kf0 = *(const b16x8*)((char*)Ks + k * 128 + ((grp * 16) ^ kswz));
      b16x8 kf1 = *(const b16x8*)((char*)Ks + k * 128 + ((64 + grp * 16) ^ kswz));
      f32x4 s = __builtin_amdgcn_mfma_f32_16x16x32_bf16(kf0, qf0, zero4, 0, 0, 0);
      sc[f] = __builtin_amdgcn_mfma_f32_16x16x32_bf16(kf1, qf1, s, 0, 0, 0);
    }

    // online softmax: lane owns q=r16; 16 in-lane scores + cross-grp reduce
    float mx = sc[0][0];
#pragma unroll
    for (int f = 0; f < 4; ++f)
#pragma unroll
      for (int r = 0; r < 4; ++r) mx = fmaxf(mx, sc[f][r]);
    mx = fmaxf(mx, __shfl_xor(mx, 16));
    mx = fmaxf(mx, __shfl_xor(mx, 32));
    float mnew = fmaxf(m2, mx);
    float corr = exp2f(m2 - mnew);
    m2 = mnew;
    f32x4 p4[4];
    float sum = 0.0f;
#pragma unroll
    for (int f = 0; f < 4; ++f)
#pragma unroll
      for (int r = 0; r < 4; ++r) {
        float p = exp2f(sc[f][r] - mnew);
        p4[f][r] = p;
        sum += p;
      }
    sum += __shfl_xor(sum, 16);
    sum += __shfl_xor(sum, 32);
    l = l * corr + sum;

    // store P row q=r16: 4x 8B packed writes (k = f*16+grp*4.. contiguous 4)
    {
      char* prow = (char*)Ps + wave * 2048 + r16 * 128;
      int qs = (r16 & 7) << 4;
#pragma unroll
      for (int f = 0; f < 4; ++f) {
        u16x4 pk;
#pragma unroll
        for (int r = 0; r < 4; ++r) pk[r] = f2bf(p4[f][r]);
        *(u16x4*)(prow + ((f * 32 + grp * 8) ^ qs)) = pk;
      }
    }

    // rescale accumulator: o rows are q = grp*4+r -> broadcast corr
    float cr[4];
#pragma unroll
    for (int r = 0; r < 4; ++r) cr[r] = __shfl(corr, grp * 4 + r, 16);
#pragma unroll
    for (int fc = 0; fc < 4; ++fc)
#pragma unroll
      for (int r = 0; r < 4; ++r) o[fc][r] *= cr[r];

    // O += P V
#pragma unroll
    for (int ks = 0; ks < 2; ++ks) {
      int pswz = (r16 & 7) << 4;
      b16x8 pa = *(const b16x8*)((char*)Ps + wave * 2048 + r16 * 128 +
                                 ((ks * 64 + grp * 16) ^ pswz));
#pragma unroll
      for (int fc = 0; fc < 4; ++fc) {
        int d = fc * 16 + r16;
        int vswz = (d & 7) << 4;
        b16x8 vb = *(const b16x8*)((char*)Vs + d * 128 +
                                   ((ks * 64 + grp * 16) ^ vswz));
        o[fc] = __builtin_amdgcn_mfma_f32_16x16x32_bf16(pa, vb, o[fc], 0, 0, 0);
      }
    }
    __syncthreads();
  }

  // O /= l ; o rows are q = grp*4+r -> broadcast l; write AO bf16
  float lr[4];
#pragma unroll
  for (int r = 0; r < 4; ++r) lr[r] = __shfl(l, grp * 4 + r, 16);
#pragma unroll
  for (int fc = 0; fc < 4; ++fc) {
    int col = head * 64 + fc * 16 + r16;
#pragma unroll
    for (int r = 0; r < 4; ++r) {
      int row = q0 + wave * 16 + grp * 4 + r;
      AO[((size_t)b * Ssz + row) * Dsz + col] = f2bf(o[fc][r] / lr[r]);
    }
  }
}

// ---------------------------------------------------------------------------
extern "C" void kernel_launch(void* const* d_in, const int* in_sizes, int n_in,
                              void* d_out, int out_size, void* d_ws,
                              size_t ws_size, hipStream_t stream) {
  const float* Q = (const float*)d_in[0];
  const float* K = (const float*)d_in[1];
  const float* V = (const float*)d_in[2];
  const float* WQ = (const float*)d_in[3];
  const float* bQ = (const float*)d_in[4];
  const float* WK = (const float*)d_in[5];
  const float* bK = (const float*)d_in[6];
  const float* WV = (const float*)d_in[7];
  const float* bV = (const float*)d_in[8];
  const float* WO = (const float*)d_in[9];
  const float* bO = (const float*)d_in[10];

  char* ws = (char*)d_ws;
  const size_t MB = 1024ull * 1024ull;
  unsigned short* Wt = (unsigned short*)(ws);             // 8 MB: 4x[n][k] bf16
  unsigned short* Pp = (unsigned short*)(ws + 8 * MB);    // Qp,Kp,Vp: 48 MB
  unsigned short* Qp = Pp;
  unsigned short* Kp = Pp + (size_t)Mrows * Dsz;
  unsigned short* Vp = Pp + 2 * (size_t)Mrows * Dsz;
  unsigned short* VpT = (unsigned short*)(ws + 56 * MB);  // 16 MB
  unsigned short* AO = Vp;  // Vp dead after vtrans -> reuse as attention out

  wconv_kernel<<<dim3(16, 16, 4), 256, 0, stream>>>(WQ, WK, WV, WO, Wt);
  proj_gemm_kernel<<<dim3(8, 64, 3), 256, 0, stream>>>(Q, K, V, Wt, bQ, bK, bV,
                                                       Pp);
  vtrans_kernel<<<dim3(16, 16, 8), 256, 0, stream>>>(Vp, VpT);
  attn_kernel<<<dim3(16, 128), 256, 0, stream>>>(Qp, Kp, VpT, AO);
  out_gemm_kernel<<<dim3(8, 64), 256, 0, stream>>>(
      AO, Wt + 3 * (size_t)Dsz * Dsz, bO, (float*)d_out);
}

// Round 3
// 221.512 us; speedup vs baseline: 1.3256x; 1.1385x over previous
//
#include <hip/hip_runtime.h>
#include <cstdint>

#define DEV __device__ __forceinline__

typedef __attribute__((ext_vector_type(4))) float f32x4;
typedef __attribute__((ext_vector_type(8))) short b16x8;
typedef __attribute__((ext_vector_type(4))) unsigned short u16x4;
typedef __attribute__((ext_vector_type(8))) unsigned short u16x8;

typedef __attribute__((address_space(1))) void gvoid_t;
typedef __attribute__((address_space(3))) void lvoid_t;

static constexpr int Bsz = 8, Ssz = 1024, Dsz = 1024;
static constexpr int Mrows = Bsz * Ssz;  // 8192

// async global->LDS, 16B per lane; lds base must be wave-uniform (HW adds lane*16)
DEV void gld16(const void* g, void* l) {
  __builtin_amdgcn_global_load_lds((gvoid_t*)(uintptr_t)g,
                                   (lvoid_t*)(unsigned)(uintptr_t)l, 16, 0, 0);
}

// fp32 -> bf16 RNE (finite inputs only)
DEV unsigned short f2bf(float x) {
  unsigned int u = __float_as_uint(x);
  u += 0x7fffu + ((u >> 16) & 1u);
  return (unsigned short)(u >> 16);
}

// ---------------------------------------------------------------------------
// Kernel 1: convert+transpose 4 weight matrices: Wt[w][n][k] = bf16(W[k][n])
// ---------------------------------------------------------------------------
__global__ __launch_bounds__(256) void wconv_kernel(
    const float* __restrict__ WQ, const float* __restrict__ WK,
    const float* __restrict__ WV, const float* __restrict__ WO,
    unsigned short* __restrict__ Wt) {
  __shared__ float tile[64][65];
  const int w = blockIdx.z;
  const float* W = (w == 0) ? WQ : (w == 1) ? WK : (w == 2) ? WV : WO;
  const int k0 = blockIdx.x * 64, n0 = blockIdx.y * 64;
  const int t = threadIdx.x;
  {
    const int r = t >> 4;
    const int c = (t & 15) * 4;
#pragma unroll
    for (int i = 0; i < 4; ++i) {
      f32x4 v = *(const f32x4*)(W + (size_t)(k0 + i * 16 + r) * Dsz + n0 + c);
      tile[i * 16 + r][c + 0] = v[0];
      tile[i * 16 + r][c + 1] = v[1];
      tile[i * 16 + r][c + 2] = v[2];
      tile[i * 16 + r][c + 3] = v[3];
    }
  }
  __syncthreads();
  {
    const int n = t >> 2;
    const int ks = (t & 3) * 16;
    unsigned short* dst =
        Wt + (size_t)w * Dsz * Dsz + (size_t)(n0 + n) * Dsz + k0 + ks;
#pragma unroll
    for (int j = 0; j < 16; j += 4) {
      u16x4 p;
#pragma unroll
      for (int jj = 0; jj < 4; ++jj) p[jj] = f2bf(tile[ks + j + jj][n]);
      *(u16x4*)(dst + j) = p;
    }
  }
}

// ---------------------------------------------------------------------------
// Kernel 1b: elementwise fp32 -> bf16 (8 elems/thread, BW-bound)
// ---------------------------------------------------------------------------
__global__ __launch_bounds__(256) void conv_kernel(
    const float* __restrict__ src, unsigned short* __restrict__ dst) {
  size_t i = ((size_t)blockIdx.x * 256 + threadIdx.x) * 8;
  f32x4 a = *(const f32x4*)(src + i);
  f32x4 b = *(const f32x4*)(src + i + 4);
  u16x8 p;
  p[0] = f2bf(a[0]); p[1] = f2bf(a[1]); p[2] = f2bf(a[2]); p[3] = f2bf(a[3]);
  p[4] = f2bf(b[0]); p[5] = f2bf(b[1]); p[6] = f2bf(b[2]); p[7] = f2bf(b[3]);
  *(u16x8*)(dst + i) = p;
}

// ---------------------------------------------------------------------------
// Kernel 2: 128x128-tile bf16 MFMA GEMM, C = relu(A @ Wt^T + bias) * outscale
//   Both operands staged via global_load_lds (16B), LDS XOR-swizzled (T2):
//   slot (row,c) holds data (row, c^(row&7)) via pre-swizzled SOURCE address.
//   OUT_MODE: 0 = fp32 row-major, 1 = bf16 row-major,
//             2 = bf16 transposed VpT[b][col][s] (fused V-transpose)
// ---------------------------------------------------------------------------
template <int OUT_MODE>
DEV void gemm_body(const unsigned short* __restrict__ A,
                   const unsigned short* __restrict__ Bt,
                   const float* __restrict__ bias, void* __restrict__ C_,
                   int m0, int n0, float outscale) {
  constexpr int Kd = 1024, Nd = 1024;
  __shared__ unsigned short Asl[128 * 64] __attribute__((aligned(16)));
  __shared__ unsigned short Bsl[128 * 64] __attribute__((aligned(16)));
  const int t = threadIdx.x, lane = t & 63, wave = t >> 6;
  const int grp = lane >> 4, r16 = lane & 15;
  const int wm = wave >> 1, wn = wave & 1;
  const int swz = (r16 & 7) << 4;  // read-side XOR (row&7 == r16&7 here)
  f32x4 acc[4][4] = {};
  for (int kt = 0; kt < Kd; kt += 64) {
#pragma unroll
    for (int j = 0; j < 4; ++j) {
      int chunk = (wave * 4 + j) * 64 + lane;
      int row = chunk >> 3, c = chunk & 7;
      int csw = c ^ (row & 7);
      gld16(Bt + (size_t)(n0 + row) * Kd + kt + csw * 8,
            (char*)Bsl + (wave * 4 + j) * 1024);
      gld16(A + (size_t)(m0 + row) * Kd + kt + csw * 8,
            (char*)Asl + (wave * 4 + j) * 1024);
    }
    __syncthreads();
#pragma unroll
    for (int cs = 0; cs < 2; ++cs) {
      b16x8 af[4], bfr[4];
#pragma unroll
      for (int mi = 0; mi < 4; ++mi)
        af[mi] = *(const b16x8*)((char*)Asl + (wm * 64 + mi * 16 + r16) * 128 +
                                 ((cs * 64 + grp * 16) ^ swz));
#pragma unroll
      for (int ni = 0; ni < 4; ++ni)
        bfr[ni] = *(const b16x8*)((char*)Bsl + (wn * 64 + ni * 16 + r16) * 128 +
                                  ((cs * 64 + grp * 16) ^ swz));
#pragma unroll
      for (int mi = 0; mi < 4; ++mi)
#pragma unroll
        for (int ni = 0; ni < 4; ++ni)
          acc[mi][ni] = __builtin_amdgcn_mfma_f32_16x16x32_bf16(
              af[mi], bfr[ni], acc[mi][ni], 0, 0, 0);
    }
    __syncthreads();
  }
  // epilogue: bias + relu (+scale); C/D layout: col=lane&15, row=(lane>>4)*4+r
#pragma unroll
  for (int mi = 0; mi < 4; ++mi) {
#pragma unroll
    for (int ni = 0; ni < 4; ++ni) {
      int col = n0 + wn * 64 + ni * 16 + r16;
      float bv = bias[col];
      int row0 = m0 + wm * 64 + mi * 16 + grp * 4;
      if constexpr (OUT_MODE == 2) {
        // VpT[b][col][s], 4 consecutive s per thread -> packed 8B store
        int bb = row0 >> 10, s = row0 & 1023;
        u16x4 pk;
#pragma unroll
        for (int r = 0; r < 4; ++r)
          pk[r] = f2bf(fmaxf(acc[mi][ni][r] + bv, 0.0f) * outscale);
        *(u16x4*)((unsigned short*)C_ +
                  (((size_t)(bb * 1024 + col)) << 10) + s) = pk;
      } else {
#pragma unroll
        for (int r = 0; r < 4; ++r) {
          float v = fmaxf(acc[mi][ni][r] + bv, 0.0f) * outscale;
          if constexpr (OUT_MODE == 1)
            ((unsigned short*)C_)[(size_t)(row0 + r) * Nd + col] = f2bf(v);
          else
            ((float*)C_)[(size_t)(row0 + r) * Nd + col] = v;
        }
      }
    }
  }
}

// Q projection pre-scaled by 1/sqrt(D)*log2(e) so attention softmax runs in
// exp2 domain with no per-score scaling (relu commutes with positive scale).
static constexpr float QSCALE = 0.03125f * 1.4426950408889634f;

// grid: 512 blocks, 1D; XCD-swizzled so the 8 n-tiles sharing an A-panel
// (and the whole 2 MB weight) land on one XCD's L2.
template <int OUT_MODE>
__global__ __launch_bounds__(256) void projz_kernel(
    const unsigned short* __restrict__ A, const unsigned short* __restrict__ Wt,
    const float* __restrict__ bias, void* __restrict__ dst, float outscale) {
  const int bid = blockIdx.x;                 // 512 = 8 xcd * 64
  const int id2 = (bid & 7) * 64 + (bid >> 3);
  const int n0 = (id2 & 7) * 128, m0 = (id2 >> 3) * 128;
  gemm_body<OUT_MODE>(A, Wt, bias, dst, m0, n0, outscale);
}

// ---------------------------------------------------------------------------
// Kernel 4: flash attention, swapped-QK^T form.
//   S^T = mfma(K, Q): lane holds q = lane&15 (one q-row), k = f*16+grp*4+r.
//   softmax: 15 in-lane fmax + 2 shfl_xor; P packed as 4x ds_write_b64.
//   Qp pre-scaled by 1/sqrt(D)*log2e, so p = exp2(s - m) directly.
// ---------------------------------------------------------------------------
__global__ __launch_bounds__(256) void attn_kernel(
    const unsigned short* __restrict__ Qp, const unsigned short* __restrict__ Kp,
    const unsigned short* __restrict__ VpT, unsigned short* __restrict__ AO) {
  __shared__ unsigned short Ks[64 * 64] __attribute__((aligned(16)));
  __shared__ unsigned short Vs[64 * 64] __attribute__((aligned(16)));
  __shared__ unsigned short Ps[4 * 16 * 64] __attribute__((aligned(16)));
  const int t = threadIdx.x, lane = t & 63, wave = t >> 6;
  const int grp = lane >> 4, r16 = lane & 15;
  // XCD swizzle: 2048 blocks = 8 xcd * 256; each XCD gets 16 complete (b,h)
  // pairs -> K/V head-slices (4 MB) stay in that XCD's L2.
  const int bid = blockIdx.x;
  const int id2 = (bid & 7) * 256 + (bid >> 3);
  const int q0 = (id2 & 15) * 64;
  const int bh = id2 >> 4;
  const int b = bh & 7, head = bh >> 3;

  // Q fragments (B-operand layout: row=lane&15 ↔ q, k = 8*grp + j)
  const int sq = q0 + wave * 16 + r16;
  const unsigned short* qbase = Qp + ((size_t)b * Ssz + sq) * Dsz + head * 64;
  b16x8 qf0 = *(const b16x8*)(qbase + grp * 8);
  b16x8 qf1 = *(const b16x8*)(qbase + 32 + grp * 8);

  f32x4 o[4] = {};
  float m2 = -1e30f, l = 0.0f;
  const f32x4 zero4 = {0.0f, 0.0f, 0.0f, 0.0f};

  for (int kv0 = 0; kv0 < Ssz; kv0 += 64) {
#pragma unroll
    for (int j = 0; j < 2; ++j) {
      int chunk = (wave * 2 + j) * 64 + lane;
      int row = chunk >> 3, c = chunk & 7;
      int csw = c ^ (row & 7);
      gld16(Kp + ((size_t)b * Ssz + kv0 + row) * Dsz + head * 64 + csw * 8,
            (char*)Ks + (wave * 2 + j) * 1024);
      gld16(VpT + ((size_t)b * Dsz + head * 64 + row) * Ssz + kv0 + csw * 8,
            (char*)Vs + (wave * 2 + j) * 1024);
    }
    __syncthreads();

    // S^T = K Q^T : sc[f] rows = k = f*16 + grp*4 + r, col = q = r16
    f32x4 sc[4];
#pragma unroll
    for (int f = 0; f < 4; ++f) {
      int k = f * 16 + r16;
      int kswz = (k & 7) << 4;
      b16x8 kf0 = *(const b16x8*)((char*)Ks + k * 128 + ((grp * 16) ^ kswz));
      b16x8 kf1 = *(const b16x8*)((char*)Ks + k * 128 + ((64 + grp * 16) ^ kswz));
      f32x4 s = __builtin_amdgcn_mfma_f32_16x16x32_bf16(kf0, qf0, zero4, 0, 0, 0);
      sc[f] = __builtin_amdgcn_mfma_f32_16x16x32_bf16(kf1, qf1, s, 0, 0, 0);
    }

    // online softmax: lane owns q=r16; 16 in-lane scores + cross-grp reduce
    float mx = sc[0][0];
#pragma unroll
    for (int f = 0; f < 4; ++f)
#pragma unroll
      for (int r = 0; r < 4; ++r) mx = fmaxf(mx, sc[f][r]);
    mx = fmaxf(mx, __shfl_xor(mx, 16));
    mx = fmaxf(mx, __shfl_xor(mx, 32));
    float mnew = fmaxf(m2, mx);
    float corr = exp2f(m2 - mnew);
    m2 = mnew;
    f32x4 p4[4];
    float sum = 0.0f;
#pragma unroll
    for (int f = 0; f < 4; ++f)
#pragma unroll
      for (int r = 0; r < 4; ++r) {
        float p = exp2f(sc[f][r] - mnew);
        p4[f][r] = p;
        sum += p;
      }
    sum += __shfl_xor(sum, 16);
    sum += __shfl_xor(sum, 32);
    l = l * corr + sum;

    // store P row q=r16: 4x 8B packed writes (k = f*16+grp*4.. contiguous 4)
    {
      char* prow = (char*)Ps + wave * 2048 + r16 * 128;
      int qs = (r16 & 7) << 4;
#pragma unroll
      for (int f = 0; f < 4; ++f) {
        u16x4 pk;
#pragma unroll
        for (int r = 0; r < 4; ++r) pk[r] = f2bf(p4[f][r]);
        *(u16x4*)(prow + ((f * 32 + grp * 8) ^ qs)) = pk;
      }
    }

    // rescale accumulator: o rows are q = grp*4+r -> broadcast corr
    float cr[4];
#pragma unroll
    for (int r = 0; r < 4; ++r) cr[r] = __shfl(corr, grp * 4 + r, 16);
#pragma unroll
    for (int fc = 0; fc < 4; ++fc)
#pragma unroll
      for (int r = 0; r < 4; ++r) o[fc][r] *= cr[r];

    // O += P V
#pragma unroll
    for (int ks = 0; ks < 2; ++ks) {
      int pswz = (r16 & 7) << 4;
      b16x8 pa = *(const b16x8*)((char*)Ps + wave * 2048 + r16 * 128 +
                                 ((ks * 64 + grp * 16) ^ pswz));
#pragma unroll
      for (int fc = 0; fc < 4; ++fc) {
        int d = fc * 16 + r16;
        int vswz = (d & 7) << 4;
        b16x8 vb = *(const b16x8*)((char*)Vs + d * 128 +
                                   ((ks * 64 + grp * 16) ^ vswz));
        o[fc] = __builtin_amdgcn_mfma_f32_16x16x32_bf16(pa, vb, o[fc], 0, 0, 0);
      }
    }
    __syncthreads();
  }

  // O /= l ; o rows are q = grp*4+r -> broadcast l; write AO bf16
  float lr[4];
#pragma unroll
  for (int r = 0; r < 4; ++r) lr[r] = __shfl(l, grp * 4 + r, 16);
#pragma unroll
  for (int fc = 0; fc < 4; ++fc) {
    int col = head * 64 + fc * 16 + r16;
#pragma unroll
    for (int r = 0; r < 4; ++r) {
      int row = q0 + wave * 16 + grp * 4 + r;
      AO[((size_t)b * Ssz + row) * Dsz + col] = f2bf(o[fc][r] / lr[r]);
    }
  }
}

// ---------------------------------------------------------------------------
extern "C" void kernel_launch(void* const* d_in, const int* in_sizes, int n_in,
                              void* d_out, int out_size, void* d_ws,
                              size_t ws_size, hipStream_t stream) {
  const float* Q = (const float*)d_in[0];
  const float* K = (const float*)d_in[1];
  const float* V = (const float*)d_in[2];
  const float* WQ = (const float*)d_in[3];
  const float* bQ = (const float*)d_in[4];
  const float* WK = (const float*)d_in[5];
  const float* bK = (const float*)d_in[6];
  const float* WV = (const float*)d_in[7];
  const float* bV = (const float*)d_in[8];
  const float* WO = (const float*)d_in[9];
  const float* bO = (const float*)d_in[10];

  char* ws = (char*)d_ws;
  const size_t MB = 1024ull * 1024ull;
  const size_t DD = (size_t)Dsz * Dsz;
  unsigned short* Wt = (unsigned short*)(ws);             // 8 MB: 4x[n][k] bf16
  unsigned short* Cbf = (unsigned short*)(ws + 8 * MB);   // 16 MB convert buf
  unsigned short* Qp = (unsigned short*)(ws + 24 * MB);   // 16 MB
  unsigned short* Kp = (unsigned short*)(ws + 40 * MB);   // 16 MB
  unsigned short* VpT = (unsigned short*)(ws + 56 * MB);  // 16 MB
  unsigned short* AO = Cbf;  // convert buf dead after last proj -> reuse

  wconv_kernel<<<dim3(16, 16, 4), 256, 0, stream>>>(WQ, WK, WV, WO, Wt);
  // per-z: convert input to bf16, then pure-gld16 GEMM (stream serializes)
  conv_kernel<<<4096, 256, 0, stream>>>(Q, Cbf);
  projz_kernel<1><<<512, 256, 0, stream>>>(Cbf, Wt, bQ, Qp, QSCALE);
  conv_kernel<<<4096, 256, 0, stream>>>(K, Cbf);
  projz_kernel<1><<<512, 256, 0, stream>>>(Cbf, Wt + DD, bK, Kp, 1.0f);
  conv_kernel<<<4096, 256, 0, stream>>>(V, Cbf);
  projz_kernel<2><<<512, 256, 0, stream>>>(Cbf, Wt + 2 * DD, bV, VpT, 1.0f);
  attn_kernel<<<2048, 256, 0, stream>>>(Qp, Kp, VpT, AO);
  projz_kernel<0><<<512, 256, 0, stream>>>(AO, Wt + 3 * DD, bO, (float*)d_out,
                                           1.0f);
}

// Round 4
// 215.047 us; speedup vs baseline: 1.3655x; 1.0301x over previous
//
#include <hip/hip_runtime.h>
#include <hip/hip_bf16.h>
#include <cstdint>

#define DEV __device__ __forceinline__

typedef __attribute__((ext_vector_type(4))) float f32x4;
typedef __attribute__((ext_vector_type(8))) short b16x8;
typedef __attribute__((ext_vector_type(4))) unsigned short u16x4;
typedef __attribute__((ext_vector_type(8))) unsigned short u16x8;
typedef __attribute__((ext_vector_type(2))) unsigned int u32x2;

typedef __attribute__((address_space(1))) void gvoid_t;
typedef __attribute__((address_space(3))) void lvoid_t;

static constexpr int Bsz = 8, Ssz = 1024, Dsz = 1024;
static constexpr int Mrows = Bsz * Ssz;  // 8192

// async global->LDS, 16B per lane; lds base must be wave-uniform (HW adds lane*16)
DEV void gld16(const void* g, void* l) {
  __builtin_amdgcn_global_load_lds((gvoid_t*)(uintptr_t)g,
                                   (lvoid_t*)(unsigned)(uintptr_t)l, 16, 0, 0);
}

// fp32 -> bf16 RNE (finite inputs only) — cold paths only
DEV unsigned short f2bf(float x) {
  unsigned int u = __float_as_uint(x);
  u += 0x7fffu + ((u >> 16) & 1u);
  return (unsigned short)(u >> 16);
}

// hot path: paired convert -> v_cvt_pk_bf16_f32
DEV unsigned int cvt2(float lo, float hi) {
  __hip_bfloat162 h = __float22bfloat162_rn(make_float2(lo, hi));
  unsigned int u;
  __builtin_memcpy(&u, &h, 4);
  return u;
}

// ---------------------------------------------------------------------------
// Kernel 1: convert+transpose 4 weight matrices: Wt[w][n][k] = bf16(W[k][n])
// ---------------------------------------------------------------------------
__global__ __launch_bounds__(256) void wconv_kernel(
    const float* __restrict__ WQ, const float* __restrict__ WK,
    const float* __restrict__ WV, const float* __restrict__ WO,
    unsigned short* __restrict__ Wt) {
  __shared__ float tile[64][65];
  const int w = blockIdx.z;
  const float* W = (w == 0) ? WQ : (w == 1) ? WK : (w == 2) ? WV : WO;
  const int k0 = blockIdx.x * 64, n0 = blockIdx.y * 64;
  const int t = threadIdx.x;
  {
    const int r = t >> 4;
    const int c = (t & 15) * 4;
#pragma unroll
    for (int i = 0; i < 4; ++i) {
      f32x4 v = *(const f32x4*)(W + (size_t)(k0 + i * 16 + r) * Dsz + n0 + c);
      tile[i * 16 + r][c + 0] = v[0];
      tile[i * 16 + r][c + 1] = v[1];
      tile[i * 16 + r][c + 2] = v[2];
      tile[i * 16 + r][c + 3] = v[3];
    }
  }
  __syncthreads();
  {
    const int n = t >> 2;
    const int ks = (t & 3) * 16;
    unsigned short* dst =
        Wt + (size_t)w * Dsz * Dsz + (size_t)(n0 + n) * Dsz + k0 + ks;
#pragma unroll
    for (int j = 0; j < 16; j += 4) {
      u16x4 p;
#pragma unroll
      for (int jj = 0; jj < 4; ++jj) p[jj] = f2bf(tile[ks + j + jj][n]);
      *(u16x4*)(dst + j) = p;
    }
  }
}

// ---------------------------------------------------------------------------
// Kernel 1b: elementwise fp32 -> bf16 (8 elems/thread, BW-bound)
// ---------------------------------------------------------------------------
__global__ __launch_bounds__(256) void conv_kernel(
    const float* __restrict__ src, unsigned short* __restrict__ dst) {
  size_t i = ((size_t)blockIdx.x * 256 + threadIdx.x) * 8;
  f32x4 a = *(const f32x4*)(src + i);
  f32x4 b = *(const f32x4*)(src + i + 4);
  u16x8 p;
  p[0] = f2bf(a[0]); p[1] = f2bf(a[1]); p[2] = f2bf(a[2]); p[3] = f2bf(a[3]);
  p[4] = f2bf(b[0]); p[5] = f2bf(b[1]); p[6] = f2bf(b[2]); p[7] = f2bf(b[3]);
  *(u16x8*)(dst + i) = p;
}

// ---------------------------------------------------------------------------
// Kernel 2: 128x128-tile bf16 MFMA GEMM, C = relu(A @ Wt^T + bias) * outscale
//   Both operands staged via global_load_lds (16B), LDS XOR-swizzled (T2):
//   slot (row,c) holds data (row, c^(row&7)) via pre-swizzled SOURCE address.
//   OUT_MODE: 0 = fp32 row-major, 1 = bf16 row-major,
//             2 = bf16 transposed VpT[b][col][s] (fused V-transpose)
// ---------------------------------------------------------------------------
template <int OUT_MODE>
DEV void gemm_body(const unsigned short* __restrict__ A,
                   const unsigned short* __restrict__ Bt,
                   const float* __restrict__ bias, void* __restrict__ C_,
                   int m0, int n0, float outscale) {
  constexpr int Kd = 1024, Nd = 1024;
  __shared__ unsigned short Asl[128 * 64] __attribute__((aligned(16)));
  __shared__ unsigned short Bsl[128 * 64] __attribute__((aligned(16)));
  const int t = threadIdx.x, lane = t & 63, wave = t >> 6;
  const int grp = lane >> 4, r16 = lane & 15;
  const int wm = wave >> 1, wn = wave & 1;
  const int swz = (r16 & 7) << 4;  // read-side XOR (row&7 == r16&7 here)
  f32x4 acc[4][4] = {};
  for (int kt = 0; kt < Kd; kt += 64) {
#pragma unroll
    for (int j = 0; j < 4; ++j) {
      int chunk = (wave * 4 + j) * 64 + lane;
      int row = chunk >> 3, c = chunk & 7;
      int csw = c ^ (row & 7);
      gld16(Bt + (size_t)(n0 + row) * Kd + kt + csw * 8,
            (char*)Bsl + (wave * 4 + j) * 1024);
      gld16(A + (size_t)(m0 + row) * Kd + kt + csw * 8,
            (char*)Asl + (wave * 4 + j) * 1024);
    }
    __syncthreads();
#pragma unroll
    for (int cs = 0; cs < 2; ++cs) {
      b16x8 af[4], bfr[4];
#pragma unroll
      for (int mi = 0; mi < 4; ++mi)
        af[mi] = *(const b16x8*)((char*)Asl + (wm * 64 + mi * 16 + r16) * 128 +
                                 ((cs * 64 + grp * 16) ^ swz));
#pragma unroll
      for (int ni = 0; ni < 4; ++ni)
        bfr[ni] = *(const b16x8*)((char*)Bsl + (wn * 64 + ni * 16 + r16) * 128 +
                                  ((cs * 64 + grp * 16) ^ swz));
#pragma unroll
      for (int mi = 0; mi < 4; ++mi)
#pragma unroll
        for (int ni = 0; ni < 4; ++ni)
          acc[mi][ni] = __builtin_amdgcn_mfma_f32_16x16x32_bf16(
              af[mi], bfr[ni], acc[mi][ni], 0, 0, 0);
    }
    __syncthreads();
  }
  // epilogue: bias + relu (+scale); C/D layout: col=lane&15, row=(lane>>4)*4+r
#pragma unroll
  for (int mi = 0; mi < 4; ++mi) {
#pragma unroll
    for (int ni = 0; ni < 4; ++ni) {
      int col = n0 + wn * 64 + ni * 16 + r16;
      float bv = bias[col];
      int row0 = m0 + wm * 64 + mi * 16 + grp * 4;
      if constexpr (OUT_MODE == 2) {
        // VpT[b][col][s], 4 consecutive s per thread -> packed 8B store
        int bb = row0 >> 10, s = row0 & 1023;
        u16x4 pk;
#pragma unroll
        for (int r = 0; r < 4; ++r)
          pk[r] = f2bf(fmaxf(acc[mi][ni][r] + bv, 0.0f) * outscale);
        *(u16x4*)((unsigned short*)C_ +
                  (((size_t)(bb * 1024 + col)) << 10) + s) = pk;
      } else {
#pragma unroll
        for (int r = 0; r < 4; ++r) {
          float v = fmaxf(acc[mi][ni][r] + bv, 0.0f) * outscale;
          if constexpr (OUT_MODE == 1)
            ((unsigned short*)C_)[(size_t)(row0 + r) * Nd + col] = f2bf(v);
          else
            ((float*)C_)[(size_t)(row0 + r) * Nd + col] = v;
        }
      }
    }
  }
}

// Q projection pre-scaled by 1/sqrt(D)*log2(e) so attention softmax runs in
// exp2 domain with no per-score scaling (relu commutes with positive scale).
static constexpr float QSCALE = 0.03125f * 1.4426950408889634f;

// grid: 512 blocks, 1D; XCD-swizzled so the 8 n-tiles sharing an A-panel
// (and the whole 2 MB weight) land on one XCD's L2.
template <int OUT_MODE>
__global__ __launch_bounds__(256) void projz_kernel(
    const unsigned short* __restrict__ A, const unsigned short* __restrict__ Wt,
    const float* __restrict__ bias, void* __restrict__ dst, float outscale) {
  const int bid = blockIdx.x;                 // 512 = 8 xcd * 64
  const int id2 = (bid & 7) * 64 + (bid >> 3);
  const int n0 = (id2 & 7) * 128, m0 = (id2 >> 3) * 128;
  gemm_body<OUT_MODE>(A, Wt, bias, dst, m0, n0, outscale);
}

// ---------------------------------------------------------------------------
// Kernel 4: flash attention, swapped-QK^T form, 2-phase pipelined staging.
//   S^T = mfma(K, Q): lane holds q = lane&15 (one q-row), k = f*16+grp*4+r.
//   softmax: max3 tree + 2 shfl_xor; defer-max (T13) skips rescale.
//   K/V double-buffered; next tile issued BEFORE compute; single
//   __syncthreads per iter (its vmcnt(0) drain lands after compute).
// ---------------------------------------------------------------------------
__global__ __launch_bounds__(256) void attn_kernel(
    const unsigned short* __restrict__ Qp, const unsigned short* __restrict__ Kp,
    const unsigned short* __restrict__ VpT, unsigned short* __restrict__ AO) {
  __shared__ unsigned short Ks[2][64 * 64] __attribute__((aligned(16)));
  __shared__ unsigned short Vs[2][64 * 64] __attribute__((aligned(16)));
  __shared__ unsigned short Ps[4 * 16 * 64] __attribute__((aligned(16)));
  const int t = threadIdx.x, lane = t & 63, wave = t >> 6;
  const int grp = lane >> 4, r16 = lane & 15;
  // XCD swizzle: 2048 blocks = 8 xcd * 256; each XCD gets 16 complete (b,h)
  // pairs -> K/V head-slices stay in that XCD's L2.
  const int bid = blockIdx.x;
  const int id2 = (bid & 7) * 256 + (bid >> 3);
  const int q0 = (id2 & 15) * 64;
  const int bh = id2 >> 4;
  const int b = bh & 7, head = bh >> 3;

  // staging addresses (row/col fixed per thread; kv0 advances)
  const int chunk0 = (wave * 2) * 64 + lane;
  const int srow0 = chunk0 >> 3, sc0 = chunk0 & 7;
  const int csw0 = sc0 ^ (srow0 & 7);
  const int chunk1 = (wave * 2 + 1) * 64 + lane;
  const int srow1 = chunk1 >> 3, sc1 = chunk1 & 7;
  const int csw1 = sc1 ^ (srow1 & 7);
  const unsigned short* kbase = Kp + ((size_t)b * Ssz) * Dsz + head * 64;
  const unsigned short* vbase = VpT + ((size_t)b * Dsz + head * 64) * Ssz;

  // Q fragments (B-operand layout: row=lane&15 ↔ q, k = 8*grp + j)
  const int sq = q0 + wave * 16 + r16;
  const unsigned short* qbase = Qp + ((size_t)b * Ssz + sq) * Dsz + head * 64;
  b16x8 qf0 = *(const b16x8*)(qbase + grp * 8);
  b16x8 qf1 = *(const b16x8*)(qbase + 32 + grp * 8);

  f32x4 o[4] = {};
  float m2 = -1e30f, l = 0.0f;
  const f32x4 zero4 = {0.0f, 0.0f, 0.0f, 0.0f};

  auto stage = [&](int kv0, int pb) {
    gld16(kbase + (size_t)(kv0 + srow0) * Dsz + csw0 * 8,
          (char*)Ks[pb] + wave * 2048);
    gld16(vbase + (size_t)srow0 * Ssz + kv0 + csw0 * 8,
          (char*)Vs[pb] + wave * 2048);
    gld16(kbase + (size_t)(kv0 + srow1) * Dsz + csw1 * 8,
          (char*)Ks[pb] + wave * 2048 + 1024);
    gld16(vbase + (size_t)srow1 * Ssz + kv0 + csw1 * 8,
          (char*)Vs[pb] + wave * 2048 + 1024);
  };

  stage(0, 0);
  __syncthreads();
  int cur = 0;

  for (int it = 0; it < 16; ++it) {
    if (it < 15) stage((it + 1) * 64, cur ^ 1);  // issue-early: overlaps compute

    // S^T = K Q^T : sc[f] rows = k = f*16 + grp*4 + r, col = q = r16
    f32x4 sc[4];
#pragma unroll
    for (int f = 0; f < 4; ++f) {
      int k = f * 16 + r16;
      int kswz = (k & 7) << 4;
      const char* kb = (const char*)Ks[cur] + k * 128;
      b16x8 kf0 = *(const b16x8*)(kb + ((grp * 16) ^ kswz));
      b16x8 kf1 = *(const b16x8*)(kb + ((64 + grp * 16) ^ kswz));
      f32x4 s = __builtin_amdgcn_mfma_f32_16x16x32_bf16(kf0, qf0, zero4, 0, 0, 0);
      sc[f] = __builtin_amdgcn_mfma_f32_16x16x32_bf16(kf1, qf1, s, 0, 0, 0);
    }

    // max over 16 in-lane values, max3-shaped tree, then cross-grp reduce
    float t0 = fmaxf(fmaxf(sc[0][0], sc[0][1]), sc[0][2]);
    float t1 = fmaxf(fmaxf(sc[0][3], sc[1][0]), sc[1][1]);
    float t2 = fmaxf(fmaxf(sc[1][2], sc[1][3]), sc[2][0]);
    float t3 = fmaxf(fmaxf(sc[2][1], sc[2][2]), sc[2][3]);
    float t4 = fmaxf(fmaxf(sc[3][0], sc[3][1]), sc[3][2]);
    float t5 = fmaxf(fmaxf(t0, t1), sc[3][3]);
    float t6 = fmaxf(fmaxf(t2, t3), t4);
    float mx = fmaxf(t5, t6);
    mx = fmaxf(mx, __shfl_xor(mx, 16));
    mx = fmaxf(mx, __shfl_xor(mx, 32));

    // defer-max (T13): skip rescale while max growth <= 11.5 (exp2 domain)
    const bool noskip = !__all(mx - m2 <= 11.5f);
    float corr = 1.0f;
    if (noskip) {
      float mnew = fmaxf(m2, mx);
      corr = exp2f(m2 - mnew);
      m2 = mnew;
    }

    f32x4 p4[4];
    float sum = 0.0f;
#pragma unroll
    for (int f = 0; f < 4; ++f)
#pragma unroll
      for (int r = 0; r < 4; ++r) {
        float p = exp2f(sc[f][r] - m2);
        p4[f][r] = p;
        sum += p;
      }
    sum += __shfl_xor(sum, 16);
    sum += __shfl_xor(sum, 32);

    // store P row q=r16: 4x 8B packed writes via v_cvt_pk_bf16_f32
    {
      char* prow = (char*)Ps + wave * 2048 + r16 * 128;
      int qs = (r16 & 7) << 4;
#pragma unroll
      for (int f = 0; f < 4; ++f) {
        u32x2 w;
        w[0] = cvt2(p4[f][0], p4[f][1]);
        w[1] = cvt2(p4[f][2], p4[f][3]);
        *(u32x2*)(prow + ((f * 32 + grp * 8) ^ qs)) = w;
      }
    }

    if (noskip) {
      l = l * corr + sum;
      // rescale accumulator: o rows are q = grp*4+r -> broadcast corr
      float cr[4];
#pragma unroll
      for (int r = 0; r < 4; ++r) cr[r] = __shfl(corr, grp * 4 + r, 16);
#pragma unroll
      for (int fc = 0; fc < 4; ++fc)
#pragma unroll
        for (int r = 0; r < 4; ++r) o[fc][r] *= cr[r];
    } else {
      l += sum;
    }

    // O += P V
#pragma unroll
    for (int ks = 0; ks < 2; ++ks) {
      int pswz = (r16 & 7) << 4;
      b16x8 pa = *(const b16x8*)((char*)Ps + wave * 2048 + r16 * 128 +
                                 ((ks * 64 + grp * 16) ^ pswz));
#pragma unroll
      for (int fc = 0; fc < 4; ++fc) {
        int d = fc * 16 + r16;
        int vswz = (d & 7) << 4;
        b16x8 vb = *(const b16x8*)((char*)Vs[cur] + d * 128 +
                                   ((ks * 64 + grp * 16) ^ vswz));
        o[fc] = __builtin_amdgcn_mfma_f32_16x16x32_bf16(pa, vb, o[fc], 0, 0, 0);
      }
    }
    __syncthreads();  // drains next-tile vmcnt after compute; read-fence for swap
    cur ^= 1;
  }

  // O /= l ; o rows are q = grp*4+r -> broadcast l; write AO bf16
  float lr[4];
#pragma unroll
  for (int r = 0; r < 4; ++r) lr[r] = __shfl(l, grp * 4 + r, 16);
#pragma unroll
  for (int fc = 0; fc < 4; ++fc) {
    int col = head * 64 + fc * 16 + r16;
#pragma unroll
    for (int r = 0; r < 4; ++r) {
      int row = q0 + wave * 16 + grp * 4 + r;
      AO[((size_t)b * Ssz + row) * Dsz + col] = f2bf(o[fc][r] / lr[r]);
    }
  }
}

// ---------------------------------------------------------------------------
extern "C" void kernel_launch(void* const* d_in, const int* in_sizes, int n_in,
                              void* d_out, int out_size, void* d_ws,
                              size_t ws_size, hipStream_t stream) {
  const float* Q = (const float*)d_in[0];
  const float* K = (const float*)d_in[1];
  const float* V = (const float*)d_in[2];
  const float* WQ = (const float*)d_in[3];
  const float* bQ = (const float*)d_in[4];
  const float* WK = (const float*)d_in[5];
  const float* bK = (const float*)d_in[6];
  const float* WV = (const float*)d_in[7];
  const float* bV = (const float*)d_in[8];
  const float* WO = (const float*)d_in[9];
  const float* bO = (const float*)d_in[10];

  char* ws = (char*)d_ws;
  const size_t MB = 1024ull * 1024ull;
  const size_t DD = (size_t)Dsz * Dsz;
  unsigned short* Wt = (unsigned short*)(ws);             // 8 MB: 4x[n][k] bf16
  unsigned short* Cbf = (unsigned short*)(ws + 8 * MB);   // 16 MB convert buf
  unsigned short* Qp = (unsigned short*)(ws + 24 * MB);   // 16 MB
  unsigned short* Kp = (unsigned short*)(ws + 40 * MB);   // 16 MB
  unsigned short* VpT = (unsigned short*)(ws + 56 * MB);  // 16 MB
  unsigned short* AO = Cbf;  // convert buf dead after last proj -> reuse

  wconv_kernel<<<dim3(16, 16, 4), 256, 0, stream>>>(WQ, WK, WV, WO, Wt);
  // per-z: convert input to bf16, then pure-gld16 GEMM (stream serializes)
  conv_kernel<<<4096, 256, 0, stream>>>(Q, Cbf);
  projz_kernel<1><<<512, 256, 0, stream>>>(Cbf, Wt, bQ, Qp, QSCALE);
  conv_kernel<<<4096, 256, 0, stream>>>(K, Cbf);
  projz_kernel<1><<<512, 256, 0, stream>>>(Cbf, Wt + DD, bK, Kp, 1.0f);
  conv_kernel<<<4096, 256, 0, stream>>>(V, Cbf);
  projz_kernel<2><<<512, 256, 0, stream>>>(Cbf, Wt + 2 * DD, bV, VpT, 1.0f);
  attn_kernel<<<2048, 256, 0, stream>>>(Qp, Kp, VpT, AO);
  projz_kernel<0><<<512, 256, 0, stream>>>(AO, Wt + 3 * DD, bO, (float*)d_out,
                                           1.0f);
}

// Round 5
// 207.940 us; speedup vs baseline: 1.4121x; 1.0342x over previous
//
#include <hip/hip_runtime.h>
#include <hip/hip_bf16.h>
#include <cstdint>

#define DEV __device__ __forceinline__

typedef __attribute__((ext_vector_type(4))) float f32x4;
typedef __attribute__((ext_vector_type(8))) short b16x8;
typedef __attribute__((ext_vector_type(4))) unsigned short u16x4;
typedef __attribute__((ext_vector_type(8))) unsigned short u16x8;
typedef __attribute__((ext_vector_type(2))) unsigned int u32x2;

typedef __attribute__((address_space(1))) void gvoid_t;
typedef __attribute__((address_space(3))) void lvoid_t;

static constexpr int Bsz = 8, Ssz = 1024, Dsz = 1024;
static constexpr int Mrows = Bsz * Ssz;  // 8192

// async global->LDS, 16B per lane; lds base must be wave-uniform (HW adds lane*16)
DEV void gld16(const void* g, void* l) {
  __builtin_amdgcn_global_load_lds((gvoid_t*)(uintptr_t)g,
                                   (lvoid_t*)(unsigned)(uintptr_t)l, 16, 0, 0);
}

// fp32 -> bf16 RNE (finite inputs only) — cold paths only
DEV unsigned short f2bf(float x) {
  unsigned int u = __float_as_uint(x);
  u += 0x7fffu + ((u >> 16) & 1u);
  return (unsigned short)(u >> 16);
}

// hot path: paired convert -> v_cvt_pk_bf16_f32
DEV unsigned int cvt2(float lo, float hi) {
  __hip_bfloat162 h = __float22bfloat162_rn(make_float2(lo, hi));
  unsigned int u;
  __builtin_memcpy(&u, &h, 4);
  return u;
}

// ---------------------------------------------------------------------------
// Kernel 1: convert+transpose 4 weight matrices: Wt[w][n][k] = bf16(W[k][n])
// ---------------------------------------------------------------------------
__global__ __launch_bounds__(256) void wconv_kernel(
    const float* __restrict__ WQ, const float* __restrict__ WK,
    const float* __restrict__ WV, const float* __restrict__ WO,
    unsigned short* __restrict__ Wt) {
  __shared__ float tile[64][65];
  const int w = blockIdx.z;
  const float* W = (w == 0) ? WQ : (w == 1) ? WK : (w == 2) ? WV : WO;
  const int k0 = blockIdx.x * 64, n0 = blockIdx.y * 64;
  const int t = threadIdx.x;
  {
    const int r = t >> 4;
    const int c = (t & 15) * 4;
#pragma unroll
    for (int i = 0; i < 4; ++i) {
      f32x4 v = *(const f32x4*)(W + (size_t)(k0 + i * 16 + r) * Dsz + n0 + c);
      tile[i * 16 + r][c + 0] = v[0];
      tile[i * 16 + r][c + 1] = v[1];
      tile[i * 16 + r][c + 2] = v[2];
      tile[i * 16 + r][c + 3] = v[3];
    }
  }
  __syncthreads();
  {
    const int n = t >> 2;
    const int ks = (t & 3) * 16;
    unsigned short* dst =
        Wt + (size_t)w * Dsz * Dsz + (size_t)(n0 + n) * Dsz + k0 + ks;
#pragma unroll
    for (int j = 0; j < 16; j += 4) {
      u16x4 p;
#pragma unroll
      for (int jj = 0; jj < 4; ++jj) p[jj] = f2bf(tile[ks + j + jj][n]);
      *(u16x4*)(dst + j) = p;
    }
  }
}

// ---------------------------------------------------------------------------
// Kernel 1b: elementwise fp32 -> bf16 (8 elems/thread, BW-bound)
// ---------------------------------------------------------------------------
__global__ __launch_bounds__(256) void conv_kernel(
    const float* __restrict__ src, unsigned short* __restrict__ dst) {
  size_t i = ((size_t)blockIdx.x * 256 + threadIdx.x) * 8;
  f32x4 a = *(const f32x4*)(src + i);
  f32x4 b = *(const f32x4*)(src + i + 4);
  u16x8 p;
  p[0] = f2bf(a[0]); p[1] = f2bf(a[1]); p[2] = f2bf(a[2]); p[3] = f2bf(a[3]);
  p[4] = f2bf(b[0]); p[5] = f2bf(b[1]); p[6] = f2bf(b[2]); p[7] = f2bf(b[3]);
  *(u16x8*)(dst + i) = p;
}

// ---------------------------------------------------------------------------
// Kernel 2: 128x128-tile bf16 MFMA GEMM, C = relu(A @ Wt^T + bias) * outscale
//   Both operands staged via global_load_lds (16B), LDS XOR-swizzled (T2):
//   slot (row,c) holds data (row, c^(row&7)) via pre-swizzled SOURCE address.
//   OUT_MODE: 0 = fp32 row-major, 1 = bf16 row-major,
//             2 = bf16 transposed VpT[b][col][s] (fused V-transpose)
// ---------------------------------------------------------------------------
template <int OUT_MODE>
DEV void gemm_body(const unsigned short* __restrict__ A,
                   const unsigned short* __restrict__ Bt,
                   const float* __restrict__ bias, void* __restrict__ C_,
                   int m0, int n0, float outscale) {
  constexpr int Kd = 1024, Nd = 1024;
  __shared__ unsigned short Asl[128 * 64] __attribute__((aligned(16)));
  __shared__ unsigned short Bsl[128 * 64] __attribute__((aligned(16)));
  const int t = threadIdx.x, lane = t & 63, wave = t >> 6;
  const int grp = lane >> 4, r16 = lane & 15;
  const int wm = wave >> 1, wn = wave & 1;
  const int swz = (r16 & 7) << 4;  // read-side XOR (row&7 == r16&7 here)
  f32x4 acc[4][4] = {};
  for (int kt = 0; kt < Kd; kt += 64) {
#pragma unroll
    for (int j = 0; j < 4; ++j) {
      int chunk = (wave * 4 + j) * 64 + lane;
      int row = chunk >> 3, c = chunk & 7;
      int csw = c ^ (row & 7);
      gld16(Bt + (size_t)(n0 + row) * Kd + kt + csw * 8,
            (char*)Bsl + (wave * 4 + j) * 1024);
      gld16(A + (size_t)(m0 + row) * Kd + kt + csw * 8,
            (char*)Asl + (wave * 4 + j) * 1024);
    }
    __syncthreads();
#pragma unroll
    for (int cs = 0; cs < 2; ++cs) {
      b16x8 af[4], bfr[4];
#pragma unroll
      for (int mi = 0; mi < 4; ++mi)
        af[mi] = *(const b16x8*)((char*)Asl + (wm * 64 + mi * 16 + r16) * 128 +
                                 ((cs * 64 + grp * 16) ^ swz));
#pragma unroll
      for (int ni = 0; ni < 4; ++ni)
        bfr[ni] = *(const b16x8*)((char*)Bsl + (wn * 64 + ni * 16 + r16) * 128 +
                                  ((cs * 64 + grp * 16) ^ swz));
#pragma unroll
      for (int mi = 0; mi < 4; ++mi)
#pragma unroll
        for (int ni = 0; ni < 4; ++ni)
          acc[mi][ni] = __builtin_amdgcn_mfma_f32_16x16x32_bf16(
              af[mi], bfr[ni], acc[mi][ni], 0, 0, 0);
    }
    __syncthreads();
  }
  // epilogue: bias + relu (+scale); C/D layout: col=lane&15, row=(lane>>4)*4+r
#pragma unroll
  for (int mi = 0; mi < 4; ++mi) {
#pragma unroll
    for (int ni = 0; ni < 4; ++ni) {
      int col = n0 + wn * 64 + ni * 16 + r16;
      float bv = bias[col];
      int row0 = m0 + wm * 64 + mi * 16 + grp * 4;
      if constexpr (OUT_MODE == 2) {
        // VpT[b][col][s], 4 consecutive s per thread -> packed 8B store
        int bb = row0 >> 10, s = row0 & 1023;
        u16x4 pk;
#pragma unroll
        for (int r = 0; r < 4; ++r)
          pk[r] = f2bf(fmaxf(acc[mi][ni][r] + bv, 0.0f) * outscale);
        *(u16x4*)((unsigned short*)C_ +
                  (((size_t)(bb * 1024 + col)) << 10) + s) = pk;
      } else {
#pragma unroll
        for (int r = 0; r < 4; ++r) {
          float v = fmaxf(acc[mi][ni][r] + bv, 0.0f) * outscale;
          if constexpr (OUT_MODE == 1)
            ((unsigned short*)C_)[(size_t)(row0 + r) * Nd + col] = f2bf(v);
          else
            ((float*)C_)[(size_t)(row0 + r) * Nd + col] = v;
        }
      }
    }
  }
}

// Q projection pre-scaled by 1/sqrt(D)*log2(e) so attention softmax runs in
// exp2 domain with no per-score scaling (relu commutes with positive scale).
static constexpr float QSCALE = 0.03125f * 1.4426950408889634f;

// grid: 512 blocks, 1D; XCD-swizzled so the 8 n-tiles sharing an A-panel
// (and the whole 2 MB weight) land on one XCD's L2.
template <int OUT_MODE>
__global__ __launch_bounds__(256) void projz_kernel(
    const unsigned short* __restrict__ A, const unsigned short* __restrict__ Wt,
    const float* __restrict__ bias, void* __restrict__ dst, float outscale) {
  const int bid = blockIdx.x;                 // 512 = 8 xcd * 64
  const int id2 = (bid & 7) * 64 + (bid >> 3);
  const int n0 = (id2 & 7) * 128, m0 = (id2 >> 3) * 128;
  gemm_body<OUT_MODE>(A, Wt, bias, dst, m0, n0, outscale);
}

// ---------------------------------------------------------------------------
// Kernel 4: flash attention, swapped-QK^T form, 2-phase pipelined staging.
//   S^T = mfma(K, Q): lane holds q = lane&15 (one q-row), k = f*16+grp*4+r.
//   l computed by the MFMA pipe via an all-ones B-fragment (o_l column);
//   defer-max (T13) common path has NO cross-lane ops at all.
// ---------------------------------------------------------------------------
__global__ __launch_bounds__(256) void attn_kernel(
    const unsigned short* __restrict__ Qp, const unsigned short* __restrict__ Kp,
    const unsigned short* __restrict__ VpT, unsigned short* __restrict__ AO) {
  __shared__ unsigned short Ks[2][64 * 64] __attribute__((aligned(16)));
  __shared__ unsigned short Vs[2][64 * 64] __attribute__((aligned(16)));
  __shared__ unsigned short Ps[4 * 16 * 64] __attribute__((aligned(16)));
  const int t = threadIdx.x, lane = t & 63, wave = t >> 6;
  const int grp = lane >> 4, r16 = lane & 15;
  // XCD swizzle: 2048 blocks = 8 xcd * 256; each XCD gets 16 complete (b,h)
  // pairs -> K/V head-slices stay in that XCD's L2.
  const int bid = blockIdx.x;
  const int id2 = (bid & 7) * 256 + (bid >> 3);
  const int q0 = (id2 & 15) * 64;
  const int bh = id2 >> 4;
  const int b = bh & 7, head = bh >> 3;

  // staging addresses (row/col fixed per thread; kv0 advances)
  const int chunk0 = (wave * 2) * 64 + lane;
  const int srow0 = chunk0 >> 3, sc0 = chunk0 & 7;
  const int csw0 = sc0 ^ (srow0 & 7);
  const int chunk1 = (wave * 2 + 1) * 64 + lane;
  const int srow1 = chunk1 >> 3, sc1 = chunk1 & 7;
  const int csw1 = sc1 ^ (srow1 & 7);
  const unsigned short* kbase = Kp + ((size_t)b * Ssz) * Dsz + head * 64;
  const unsigned short* vbase = VpT + ((size_t)b * Dsz + head * 64) * Ssz;

  // Q fragments (B-operand layout: row=lane&15 ↔ q, k = 8*grp + j)
  const int sq = q0 + wave * 16 + r16;
  const unsigned short* qbase = Qp + ((size_t)b * Ssz + sq) * Dsz + head * 64;
  b16x8 qf0 = *(const b16x8*)(qbase + grp * 8);
  b16x8 qf1 = *(const b16x8*)(qbase + 32 + grp * 8);

  f32x4 o[4] = {};
  f32x4 o_l = {};  // l accumulated by the MFMA pipe (ones-column)
  float m2 = -1e30f;
  const f32x4 zero4 = {0.0f, 0.0f, 0.0f, 0.0f};
  const b16x8 ones = {16256, 16256, 16256, 16256,
                      16256, 16256, 16256, 16256};  // bf16 1.0 x8

  auto stage = [&](int kv0, int pb) {
    gld16(kbase + (size_t)(kv0 + srow0) * Dsz + csw0 * 8,
          (char*)Ks[pb] + wave * 2048);
    gld16(vbase + (size_t)srow0 * Ssz + kv0 + csw0 * 8,
          (char*)Vs[pb] + wave * 2048);
    gld16(kbase + (size_t)(kv0 + srow1) * Dsz + csw1 * 8,
          (char*)Ks[pb] + wave * 2048 + 1024);
    gld16(vbase + (size_t)srow1 * Ssz + kv0 + csw1 * 8,
          (char*)Vs[pb] + wave * 2048 + 1024);
  };

  stage(0, 0);
  __syncthreads();
  int cur = 0;

  for (int it = 0; it < 16; ++it) {
    if (it < 15) stage((it + 1) * 64, cur ^ 1);  // issue-early: overlaps compute

    // S^T = K Q^T : sc[f] rows = k = f*16 + grp*4 + r, col = q = r16
    __builtin_amdgcn_s_setprio(1);
    f32x4 sc[4];
#pragma unroll
    for (int f = 0; f < 4; ++f) {
      int k = f * 16 + r16;
      int kswz = (k & 7) << 4;
      const char* kb = (const char*)Ks[cur] + k * 128;
      b16x8 kf0 = *(const b16x8*)(kb + ((grp * 16) ^ kswz));
      b16x8 kf1 = *(const b16x8*)(kb + ((64 + grp * 16) ^ kswz));
      f32x4 s = __builtin_amdgcn_mfma_f32_16x16x32_bf16(kf0, qf0, zero4, 0, 0, 0);
      sc[f] = __builtin_amdgcn_mfma_f32_16x16x32_bf16(kf1, qf1, s, 0, 0, 0);
    }
    __builtin_amdgcn_s_setprio(0);

    // per-lane max over 16 in-lane values (max3-shaped tree)
    float t0 = fmaxf(fmaxf(sc[0][0], sc[0][1]), sc[0][2]);
    float t1 = fmaxf(fmaxf(sc[0][3], sc[1][0]), sc[1][1]);
    float t2 = fmaxf(fmaxf(sc[1][2], sc[1][3]), sc[2][0]);
    float t3 = fmaxf(fmaxf(sc[2][1], sc[2][2]), sc[2][3]);
    float t4 = fmaxf(fmaxf(sc[3][0], sc[3][1]), sc[3][2]);
    float t5 = fmaxf(fmaxf(t0, t1), sc[3][3]);
    float t6 = fmaxf(fmaxf(t2, t3), t4);
    float mx = fmaxf(t5, t6);

    // defer-max (T13): wave-uniform predicate on PER-LANE maxima; the true
    // cross-lane max is only needed in the cold (rescale) branch.
    if (!__all(mx - m2 <= 11.5f)) {
      mx = fmaxf(mx, __shfl_xor(mx, 16));
      mx = fmaxf(mx, __shfl_xor(mx, 32));
      float mnew = fmaxf(m2, mx);
      float corr = exp2f(m2 - mnew);
      m2 = mnew;
      float cr[4];
#pragma unroll
      for (int r = 0; r < 4; ++r) cr[r] = __shfl(corr, grp * 4 + r, 16);
#pragma unroll
      for (int fc = 0; fc < 4; ++fc)
#pragma unroll
        for (int r = 0; r < 4; ++r) o[fc][r] *= cr[r];
#pragma unroll
      for (int r = 0; r < 4; ++r) o_l[r] *= cr[r];
    }

    // p = exp2(s - m2); pack P row q=r16: 4x 8B writes via v_cvt_pk_bf16_f32
    {
      char* prow = (char*)Ps + wave * 2048 + r16 * 128;
      int qs = (r16 & 7) << 4;
#pragma unroll
      for (int f = 0; f < 4; ++f) {
        u32x2 w;
        w[0] = cvt2(exp2f(sc[f][0] - m2), exp2f(sc[f][1] - m2));
        w[1] = cvt2(exp2f(sc[f][2] - m2), exp2f(sc[f][3] - m2));
        *(u32x2*)(prow + ((f * 32 + grp * 8) ^ qs)) = w;
      }
    }

    // O += P V ; l += P 1 (ones-column on the MFMA pipe)
    __builtin_amdgcn_s_setprio(1);
#pragma unroll
    for (int ks = 0; ks < 2; ++ks) {
      int pswz = (r16 & 7) << 4;
      b16x8 pa = *(const b16x8*)((char*)Ps + wave * 2048 + r16 * 128 +
                                 ((ks * 64 + grp * 16) ^ pswz));
      o_l = __builtin_amdgcn_mfma_f32_16x16x32_bf16(pa, ones, o_l, 0, 0, 0);
#pragma unroll
      for (int fc = 0; fc < 4; ++fc) {
        int d = fc * 16 + r16;
        int vswz = (d & 7) << 4;
        b16x8 vb = *(const b16x8*)((char*)Vs[cur] + d * 128 +
                                   ((ks * 64 + grp * 16) ^ vswz));
        o[fc] = __builtin_amdgcn_mfma_f32_16x16x32_bf16(pa, vb, o[fc], 0, 0, 0);
      }
    }
    __builtin_amdgcn_s_setprio(0);
    __syncthreads();  // drains next-tile vmcnt after compute; read-fence for swap
    cur ^= 1;
  }

  // O /= l ; o and o_l share the D-layout (row q = grp*4+r) -> no broadcast
#pragma unroll
  for (int fc = 0; fc < 4; ++fc) {
    int col = head * 64 + fc * 16 + r16;
#pragma unroll
    for (int r = 0; r < 4; ++r) {
      int row = q0 + wave * 16 + grp * 4 + r;
      AO[((size_t)b * Ssz + row) * Dsz + col] = f2bf(o[fc][r] / o_l[r]);
    }
  }
}

// ---------------------------------------------------------------------------
extern "C" void kernel_launch(void* const* d_in, const int* in_sizes, int n_in,
                              void* d_out, int out_size, void* d_ws,
                              size_t ws_size, hipStream_t stream) {
  const float* Q = (const float*)d_in[0];
  const float* K = (const float*)d_in[1];
  const float* V = (const float*)d_in[2];
  const float* WQ = (const float*)d_in[3];
  const float* bQ = (const float*)d_in[4];
  const float* WK = (const float*)d_in[5];
  const float* bK = (const float*)d_in[6];
  const float* WV = (const float*)d_in[7];
  const float* bV = (const float*)d_in[8];
  const float* WO = (const float*)d_in[9];
  const float* bO = (const float*)d_in[10];

  char* ws = (char*)d_ws;
  const size_t MB = 1024ull * 1024ull;
  const size_t DD = (size_t)Dsz * Dsz;
  unsigned short* Wt = (unsigned short*)(ws);             // 8 MB: 4x[n][k] bf16
  unsigned short* Cbf = (unsigned short*)(ws + 8 * MB);   // 16 MB convert buf
  unsigned short* Qp = (unsigned short*)(ws + 24 * MB);   // 16 MB
  unsigned short* Kp = (unsigned short*)(ws + 40 * MB);   // 16 MB
  unsigned short* VpT = (unsigned short*)(ws + 56 * MB);  // 16 MB
  unsigned short* AO = Cbf;  // convert buf dead after last proj -> reuse

  wconv_kernel<<<dim3(16, 16, 4), 256, 0, stream>>>(WQ, WK, WV, WO, Wt);
  // per-z: convert input to bf16, then pure-gld16 GEMM (stream serializes)
  conv_kernel<<<4096, 256, 0, stream>>>(Q, Cbf);
  projz_kernel<1><<<512, 256, 0, stream>>>(Cbf, Wt, bQ, Qp, QSCALE);
  conv_kernel<<<4096, 256, 0, stream>>>(K, Cbf);
  projz_kernel<1><<<512, 256, 0, stream>>>(Cbf, Wt + DD, bK, Kp, 1.0f);
  conv_kernel<<<4096, 256, 0, stream>>>(V, Cbf);
  projz_kernel<2><<<512, 256, 0, stream>>>(Cbf, Wt + 2 * DD, bV, VpT, 1.0f);
  attn_kernel<<<2048, 256, 0, stream>>>(Qp, Kp, VpT, AO);
  projz_kernel<0><<<512, 256, 0, stream>>>(AO, Wt + 3 * DD, bO, (float*)d_out,
                                           1.0f);
}

// Round 6
// 203.285 us; speedup vs baseline: 1.4445x; 1.0229x over previous
//
#include <hip/hip_runtime.h>
#include <hip/hip_bf16.h>
#include <cstdint>

#define DEV __device__ __forceinline__

typedef __attribute__((ext_vector_type(4))) float f32x4;
typedef __attribute__((ext_vector_type(8))) short b16x8;
typedef __attribute__((ext_vector_type(4))) unsigned short u16x4;
typedef __attribute__((ext_vector_type(8))) unsigned short u16x8;
typedef __attribute__((ext_vector_type(2))) unsigned int u32x2;

typedef __attribute__((address_space(1))) void gvoid_t;
typedef __attribute__((address_space(3))) void lvoid_t;

static constexpr int Bsz = 8, Ssz = 1024, Dsz = 1024;
static constexpr int Mrows = Bsz * Ssz;  // 8192

// async global->LDS, 16B per lane; lds base must be wave-uniform (HW adds lane*16)
DEV void gld16(const void* g, void* l) {
  __builtin_amdgcn_global_load_lds((gvoid_t*)(uintptr_t)g,
                                   (lvoid_t*)(unsigned)(uintptr_t)l, 16, 0, 0);
}

// fp32 -> bf16 RNE (finite inputs only) — cold paths only
DEV unsigned short f2bf(float x) {
  unsigned int u = __float_as_uint(x);
  u += 0x7fffu + ((u >> 16) & 1u);
  return (unsigned short)(u >> 16);
}

// hot path: paired convert -> v_cvt_pk_bf16_f32
DEV unsigned int cvt2(float lo, float hi) {
  __hip_bfloat162 h = __float22bfloat162_rn(make_float2(lo, hi));
  unsigned int u;
  __builtin_memcpy(&u, &h, 4);
  return u;
}

// ---------------------------------------------------------------------------
// Kernel 1: convert+transpose 4 weight matrices: Wt[w][n][k] = bf16(W[k][n])
// ---------------------------------------------------------------------------
__global__ __launch_bounds__(256) void wconv_kernel(
    const float* __restrict__ WQ, const float* __restrict__ WK,
    const float* __restrict__ WV, const float* __restrict__ WO,
    unsigned short* __restrict__ Wt) {
  __shared__ float tile[64][65];
  const int w = blockIdx.z;
  const float* W = (w == 0) ? WQ : (w == 1) ? WK : (w == 2) ? WV : WO;
  const int k0 = blockIdx.x * 64, n0 = blockIdx.y * 64;
  const int t = threadIdx.x;
  {
    const int r = t >> 4;
    const int c = (t & 15) * 4;
#pragma unroll
    for (int i = 0; i < 4; ++i) {
      f32x4 v = *(const f32x4*)(W + (size_t)(k0 + i * 16 + r) * Dsz + n0 + c);
      tile[i * 16 + r][c + 0] = v[0];
      tile[i * 16 + r][c + 1] = v[1];
      tile[i * 16 + r][c + 2] = v[2];
      tile[i * 16 + r][c + 3] = v[3];
    }
  }
  __syncthreads();
  {
    const int n = t >> 2;
    const int ks = (t & 3) * 16;
    unsigned short* dst =
        Wt + (size_t)w * Dsz * Dsz + (size_t)(n0 + n) * Dsz + k0 + ks;
#pragma unroll
    for (int j = 0; j < 16; j += 4) {
      u16x4 p;
#pragma unroll
      for (int jj = 0; jj < 4; ++jj) p[jj] = f2bf(tile[ks + j + jj][n]);
      *(u16x4*)(dst + j) = p;
    }
  }
}

// ---------------------------------------------------------------------------
// Kernel 1b: elementwise fp32 -> bf16 (8 elems/thread, BW-bound)
// ---------------------------------------------------------------------------
__global__ __launch_bounds__(256) void conv_kernel(
    const float* __restrict__ src, unsigned short* __restrict__ dst) {
  size_t i = ((size_t)blockIdx.x * 256 + threadIdx.x) * 8;
  f32x4 a = *(const f32x4*)(src + i);
  f32x4 b = *(const f32x4*)(src + i + 4);
  u16x8 p;
  p[0] = f2bf(a[0]); p[1] = f2bf(a[1]); p[2] = f2bf(a[2]); p[3] = f2bf(a[3]);
  p[4] = f2bf(b[0]); p[5] = f2bf(b[1]); p[6] = f2bf(b[2]); p[7] = f2bf(b[3]);
  *(u16x8*)(dst + i) = p;
}

// ---------------------------------------------------------------------------
// Kernel 2: 128x128-tile bf16 MFMA GEMM, C = relu(A @ Wt^T + bias) * outscale
//   Both operands staged via global_load_lds (16B), LDS XOR-swizzled (T2):
//   slot (row,c) holds data (row, c^(row&7)) via pre-swizzled SOURCE address.
//   OUT_MODE: 0 = fp32 row-major, 1 = bf16 row-major,
//             2 = bf16 transposed VpT[b][col][s] (fused V-transpose)
// ---------------------------------------------------------------------------
template <int OUT_MODE>
DEV void gemm_body(const unsigned short* __restrict__ A,
                   const unsigned short* __restrict__ Bt,
                   const float* __restrict__ bias, void* __restrict__ C_,
                   int m0, int n0, float outscale) {
  constexpr int Kd = 1024, Nd = 1024;
  __shared__ unsigned short Asl[128 * 64] __attribute__((aligned(16)));
  __shared__ unsigned short Bsl[128 * 64] __attribute__((aligned(16)));
  const int t = threadIdx.x, lane = t & 63, wave = t >> 6;
  const int grp = lane >> 4, r16 = lane & 15;
  const int wm = wave >> 1, wn = wave & 1;
  const int swz = (r16 & 7) << 4;  // read-side XOR (row&7 == r16&7 here)
  f32x4 acc[4][4] = {};
  for (int kt = 0; kt < Kd; kt += 64) {
#pragma unroll
    for (int j = 0; j < 4; ++j) {
      int chunk = (wave * 4 + j) * 64 + lane;
      int row = chunk >> 3, c = chunk & 7;
      int csw = c ^ (row & 7);
      gld16(Bt + (size_t)(n0 + row) * Kd + kt + csw * 8,
            (char*)Bsl + (wave * 4 + j) * 1024);
      gld16(A + (size_t)(m0 + row) * Kd + kt + csw * 8,
            (char*)Asl + (wave * 4 + j) * 1024);
    }
    __syncthreads();
#pragma unroll
    for (int cs = 0; cs < 2; ++cs) {
      b16x8 af[4], bfr[4];
#pragma unroll
      for (int mi = 0; mi < 4; ++mi)
        af[mi] = *(const b16x8*)((char*)Asl + (wm * 64 + mi * 16 + r16) * 128 +
                                 ((cs * 64 + grp * 16) ^ swz));
#pragma unroll
      for (int ni = 0; ni < 4; ++ni)
        bfr[ni] = *(const b16x8*)((char*)Bsl + (wn * 64 + ni * 16 + r16) * 128 +
                                  ((cs * 64 + grp * 16) ^ swz));
#pragma unroll
      for (int mi = 0; mi < 4; ++mi)
#pragma unroll
        for (int ni = 0; ni < 4; ++ni)
          acc[mi][ni] = __builtin_amdgcn_mfma_f32_16x16x32_bf16(
              af[mi], bfr[ni], acc[mi][ni], 0, 0, 0);
    }
    __syncthreads();
  }
  // epilogue: bias + relu (+scale); C/D layout: col=lane&15, row=(lane>>4)*4+r
#pragma unroll
  for (int mi = 0; mi < 4; ++mi) {
#pragma unroll
    for (int ni = 0; ni < 4; ++ni) {
      int col = n0 + wn * 64 + ni * 16 + r16;
      float bv = bias[col];
      int row0 = m0 + wm * 64 + mi * 16 + grp * 4;
      if constexpr (OUT_MODE == 2) {
        // VpT[b][col][s], 4 consecutive s per thread -> packed 8B store
        int bb = row0 >> 10, s = row0 & 1023;
        u16x4 pk;
#pragma unroll
        for (int r = 0; r < 4; ++r)
          pk[r] = f2bf(fmaxf(acc[mi][ni][r] + bv, 0.0f) * outscale);
        *(u16x4*)((unsigned short*)C_ +
                  (((size_t)(bb * 1024 + col)) << 10) + s) = pk;
      } else {
#pragma unroll
        for (int r = 0; r < 4; ++r) {
          float v = fmaxf(acc[mi][ni][r] + bv, 0.0f) * outscale;
          if constexpr (OUT_MODE == 1)
            ((unsigned short*)C_)[(size_t)(row0 + r) * Nd + col] = f2bf(v);
          else
            ((float*)C_)[(size_t)(row0 + r) * Nd + col] = v;
        }
      }
    }
  }
}

// Q projection pre-scaled by 1/sqrt(D)*log2(e) so attention softmax runs in
// exp2 domain with no per-score scaling (relu commutes with positive scale).
static constexpr float QSCALE = 0.03125f * 1.4426950408889634f;

// grid: 512 blocks, 1D; XCD-swizzled so the 8 n-tiles sharing an A-panel
// (and the whole 2 MB weight) land on one XCD's L2.
template <int OUT_MODE>
__global__ __launch_bounds__(256) void projz_kernel(
    const unsigned short* __restrict__ A, const unsigned short* __restrict__ Wt,
    const float* __restrict__ bias, void* __restrict__ dst, float outscale) {
  const int bid = blockIdx.x;                 // 512 = 8 xcd * 64
  const int id2 = (bid & 7) * 64 + (bid >> 3);
  const int n0 = (id2 & 7) * 128, m0 = (id2 >> 3) * 128;
  gemm_body<OUT_MODE>(A, Wt, bias, dst, m0, n0, outscale);
}

// ---------------------------------------------------------------------------
// Kernel 4: flash attention, swapped-QK^T, NO max tracking.
//   Post-ReLU Q,K >= 0  =>  scores s >= 0, bounded (<~26 in exp2 domain)
//   => p = exp2(s) directly: no overflow (fp32 limit 2^127), no underflow
//   (p >= 1), l = sum(p) fp32-safe. Softmax shift-invariance makes o/l exact.
//   Softmax per iter: 16 v_exp + 8 cvt_pk + 4 ds_write. No cross-lane ops,
//   no branches. l accumulated on the MFMA pipe via ones-column.
// ---------------------------------------------------------------------------
__global__ __launch_bounds__(256) void attn_kernel(
    const unsigned short* __restrict__ Qp, const unsigned short* __restrict__ Kp,
    const unsigned short* __restrict__ VpT, unsigned short* __restrict__ AO) {
  __shared__ unsigned short Ks[2][64 * 64] __attribute__((aligned(16)));
  __shared__ unsigned short Vs[2][64 * 64] __attribute__((aligned(16)));
  __shared__ unsigned short Ps[4 * 16 * 64] __attribute__((aligned(16)));
  const int t = threadIdx.x, lane = t & 63, wave = t >> 6;
  const int grp = lane >> 4, r16 = lane & 15;
  // XCD swizzle: 2048 blocks = 8 xcd * 256; each XCD gets 16 complete (b,h)
  // pairs -> K/V head-slices stay in that XCD's L2.
  const int bid = blockIdx.x;
  const int id2 = (bid & 7) * 256 + (bid >> 3);
  const int q0 = (id2 & 15) * 64;
  const int bh = id2 >> 4;
  const int b = bh & 7, head = bh >> 3;

  // staging addresses (row/col fixed per thread; kv0 advances)
  const int chunk0 = (wave * 2) * 64 + lane;
  const int srow0 = chunk0 >> 3, sc0 = chunk0 & 7;
  const int csw0 = sc0 ^ (srow0 & 7);
  const int chunk1 = (wave * 2 + 1) * 64 + lane;
  const int srow1 = chunk1 >> 3, sc1 = chunk1 & 7;
  const int csw1 = sc1 ^ (srow1 & 7);
  const unsigned short* kbase = Kp + ((size_t)b * Ssz) * Dsz + head * 64;
  const unsigned short* vbase = VpT + ((size_t)b * Dsz + head * 64) * Ssz;

  // Q fragments (B-operand layout: row=lane&15 ↔ q, k = 8*grp + j)
  const int sq = q0 + wave * 16 + r16;
  const unsigned short* qbase = Qp + ((size_t)b * Ssz + sq) * Dsz + head * 64;
  b16x8 qf0 = *(const b16x8*)(qbase + grp * 8);
  b16x8 qf1 = *(const b16x8*)(qbase + 32 + grp * 8);

  f32x4 o[4] = {};
  f32x4 o_l = {};  // l accumulated by the MFMA pipe (ones-column)
  const f32x4 zero4 = {0.0f, 0.0f, 0.0f, 0.0f};
  const b16x8 ones = {16256, 16256, 16256, 16256,
                      16256, 16256, 16256, 16256};  // bf16 1.0 x8

  auto stage = [&](int kv0, int pb) {
    gld16(kbase + (size_t)(kv0 + srow0) * Dsz + csw0 * 8,
          (char*)Ks[pb] + wave * 2048);
    gld16(vbase + (size_t)srow0 * Ssz + kv0 + csw0 * 8,
          (char*)Vs[pb] + wave * 2048);
    gld16(kbase + (size_t)(kv0 + srow1) * Dsz + csw1 * 8,
          (char*)Ks[pb] + wave * 2048 + 1024);
    gld16(vbase + (size_t)srow1 * Ssz + kv0 + csw1 * 8,
          (char*)Vs[pb] + wave * 2048 + 1024);
  };

  stage(0, 0);
  __syncthreads();
  int cur = 0;

  for (int it = 0; it < 16; ++it) {
    if (it < 15) stage((it + 1) * 64, cur ^ 1);  // issue-early: overlaps compute

    // S^T = K Q^T : sc[f] rows = k = f*16 + grp*4 + r, col = q = r16
    __builtin_amdgcn_s_setprio(1);
    f32x4 sc[4];
#pragma unroll
    for (int f = 0; f < 4; ++f) {
      int k = f * 16 + r16;
      int kswz = (k & 7) << 4;
      const char* kb = (const char*)Ks[cur] + k * 128;
      b16x8 kf0 = *(const b16x8*)(kb + ((grp * 16) ^ kswz));
      b16x8 kf1 = *(const b16x8*)(kb + ((64 + grp * 16) ^ kswz));
      f32x4 s = __builtin_amdgcn_mfma_f32_16x16x32_bf16(kf0, qf0, zero4, 0, 0, 0);
      sc[f] = __builtin_amdgcn_mfma_f32_16x16x32_bf16(kf1, qf1, s, 0, 0, 0);
    }
    __builtin_amdgcn_s_setprio(0);

    // p = exp2(s); pack P row q=r16: 4x 8B writes via v_cvt_pk_bf16_f32
    {
      char* prow = (char*)Ps + wave * 2048 + r16 * 128;
      int qs = (r16 & 7) << 4;
#pragma unroll
      for (int f = 0; f < 4; ++f) {
        u32x2 w;
        w[0] = cvt2(exp2f(sc[f][0]), exp2f(sc[f][1]));
        w[1] = cvt2(exp2f(sc[f][2]), exp2f(sc[f][3]));
        *(u32x2*)(prow + ((f * 32 + grp * 8) ^ qs)) = w;
      }
    }

    // O += P V ; l += P 1 (ones-column on the MFMA pipe)
    __builtin_amdgcn_s_setprio(1);
#pragma unroll
    for (int ks = 0; ks < 2; ++ks) {
      int pswz = (r16 & 7) << 4;
      b16x8 pa = *(const b16x8*)((char*)Ps + wave * 2048 + r16 * 128 +
                                 ((ks * 64 + grp * 16) ^ pswz));
      o_l = __builtin_amdgcn_mfma_f32_16x16x32_bf16(pa, ones, o_l, 0, 0, 0);
#pragma unroll
      for (int fc = 0; fc < 4; ++fc) {
        int d = fc * 16 + r16;
        int vswz = (d & 7) << 4;
        b16x8 vb = *(const b16x8*)((char*)Vs[cur] + d * 128 +
                                   ((ks * 64 + grp * 16) ^ vswz));
        o[fc] = __builtin_amdgcn_mfma_f32_16x16x32_bf16(pa, vb, o[fc], 0, 0, 0);
      }
    }
    __builtin_amdgcn_s_setprio(0);
    __syncthreads();  // drains next-tile vmcnt after compute; read-fence for swap
    cur ^= 1;
  }

  // O /= l ; o and o_l share the D-layout (row q = grp*4+r) -> no broadcast
#pragma unroll
  for (int fc = 0; fc < 4; ++fc) {
    int col = head * 64 + fc * 16 + r16;
#pragma unroll
    for (int r = 0; r < 4; ++r) {
      int row = q0 + wave * 16 + grp * 4 + r;
      AO[((size_t)b * Ssz + row) * Dsz + col] = f2bf(o[fc][r] / o_l[r]);
    }
  }
}

// ---------------------------------------------------------------------------
extern "C" void kernel_launch(void* const* d_in, const int* in_sizes, int n_in,
                              void* d_out, int out_size, void* d_ws,
                              size_t ws_size, hipStream_t stream) {
  const float* Q = (const float*)d_in[0];
  const float* K = (const float*)d_in[1];
  const float* V = (const float*)d_in[2];
  const float* WQ = (const float*)d_in[3];
  const float* bQ = (const float*)d_in[4];
  const float* WK = (const float*)d_in[5];
  const float* bK = (const float*)d_in[6];
  const float* WV = (const float*)d_in[7];
  const float* bV = (const float*)d_in[8];
  const float* WO = (const float*)d_in[9];
  const float* bO = (const float*)d_in[10];

  char* ws = (char*)d_ws;
  const size_t MB = 1024ull * 1024ull;
  const size_t DD = (size_t)Dsz * Dsz;
  unsigned short* Wt = (unsigned short*)(ws);             // 8 MB: 4x[n][k] bf16
  unsigned short* Cbf = (unsigned short*)(ws + 8 * MB);   // 16 MB convert buf
  unsigned short* Qp = (unsigned short*)(ws + 24 * MB);   // 16 MB
  unsigned short* Kp = (unsigned short*)(ws + 40 * MB);   // 16 MB
  unsigned short* VpT = (unsigned short*)(ws + 56 * MB);  // 16 MB
  unsigned short* AO = Cbf;  // convert buf dead after last proj -> reuse

  wconv_kernel<<<dim3(16, 16, 4), 256, 0, stream>>>(WQ, WK, WV, WO, Wt);
  // per-z: convert input to bf16, then pure-gld16 GEMM (stream serializes)
  conv_kernel<<<4096, 256, 0, stream>>>(Q, Cbf);
  projz_kernel<1><<<512, 256, 0, stream>>>(Cbf, Wt, bQ, Qp, QSCALE);
  conv_kernel<<<4096, 256, 0, stream>>>(K, Cbf);
  projz_kernel<1><<<512, 256, 0, stream>>>(Cbf, Wt + DD, bK, Kp, 1.0f);
  conv_kernel<<<4096, 256, 0, stream>>>(V, Cbf);
  projz_kernel<2><<<512, 256, 0, stream>>>(Cbf, Wt + 2 * DD, bV, VpT, 1.0f);
  attn_kernel<<<2048, 256, 0, stream>>>(Qp, Kp, VpT, AO);
  projz_kernel<0><<<512, 256, 0, stream>>>(AO, Wt + 3 * DD, bO, (float*)d_out,
                                           1.0f);
}

// Round 7
// 199.305 us; speedup vs baseline: 1.4733x; 1.0200x over previous
//
#include <hip/hip_runtime.h>
#include <hip/hip_bf16.h>
#include <cstdint>

#define DEV __device__ __forceinline__

typedef __attribute__((ext_vector_type(4))) float f32x4;
typedef __attribute__((ext_vector_type(8))) short b16x8;
typedef __attribute__((ext_vector_type(4))) unsigned short u16x4;
typedef __attribute__((ext_vector_type(8))) unsigned short u16x8;
typedef __attribute__((ext_vector_type(2))) unsigned int u32x2;

typedef __attribute__((address_space(1))) void gvoid_t;
typedef __attribute__((address_space(3))) void lvoid_t;

static constexpr int Bsz = 8, Ssz = 1024, Dsz = 1024;
static constexpr int Mrows = Bsz * Ssz;  // 8192

// async global->LDS, 16B per lane; lds base must be wave-uniform (HW adds lane*16)
DEV void gld16(const void* g, void* l) {
  __builtin_amdgcn_global_load_lds((gvoid_t*)(uintptr_t)g,
                                   (lvoid_t*)(unsigned)(uintptr_t)l, 16, 0, 0);
}

// fp32 -> bf16 RNE (finite inputs only) — cold paths only
DEV unsigned short f2bf(float x) {
  unsigned int u = __float_as_uint(x);
  u += 0x7fffu + ((u >> 16) & 1u);
  return (unsigned short)(u >> 16);
}

// hot path: paired convert -> v_cvt_pk_bf16_f32
DEV unsigned int cvt2(float lo, float hi) {
  __hip_bfloat162 h = __float22bfloat162_rn(make_float2(lo, hi));
  unsigned int u;
  __builtin_memcpy(&u, &h, 4);
  return u;
}

// ---------------------------------------------------------------------------
// Kernel 1: convert+transpose 4 weight matrices: Wt[w][n][k] = bf16(W[k][n])
// ---------------------------------------------------------------------------
__global__ __launch_bounds__(256) void wconv_kernel(
    const float* __restrict__ WQ, const float* __restrict__ WK,
    const float* __restrict__ WV, const float* __restrict__ WO,
    unsigned short* __restrict__ Wt) {
  __shared__ float tile[64][65];
  const int w = blockIdx.z;
  const float* W = (w == 0) ? WQ : (w == 1) ? WK : (w == 2) ? WV : WO;
  const int k0 = blockIdx.x * 64, n0 = blockIdx.y * 64;
  const int t = threadIdx.x;
  {
    const int r = t >> 4;
    const int c = (t & 15) * 4;
#pragma unroll
    for (int i = 0; i < 4; ++i) {
      f32x4 v = *(const f32x4*)(W + (size_t)(k0 + i * 16 + r) * Dsz + n0 + c);
      tile[i * 16 + r][c + 0] = v[0];
      tile[i * 16 + r][c + 1] = v[1];
      tile[i * 16 + r][c + 2] = v[2];
      tile[i * 16 + r][c + 3] = v[3];
    }
  }
  __syncthreads();
  {
    const int n = t >> 2;
    const int ks = (t & 3) * 16;
    unsigned short* dst =
        Wt + (size_t)w * Dsz * Dsz + (size_t)(n0 + n) * Dsz + k0 + ks;
#pragma unroll
    for (int j = 0; j < 16; j += 4) {
      u16x4 p;
#pragma unroll
      for (int jj = 0; jj < 4; ++jj) p[jj] = f2bf(tile[ks + j + jj][n]);
      *(u16x4*)(dst + j) = p;
    }
  }
}

// ---------------------------------------------------------------------------
// Kernel 1b: elementwise fp32 -> bf16 (8 elems/thread, BW-bound)
// ---------------------------------------------------------------------------
__global__ __launch_bounds__(256) void conv_kernel(
    const float* __restrict__ src, unsigned short* __restrict__ dst) {
  size_t i = ((size_t)blockIdx.x * 256 + threadIdx.x) * 8;
  f32x4 a = *(const f32x4*)(src + i);
  f32x4 b = *(const f32x4*)(src + i + 4);
  u16x8 p;
  p[0] = f2bf(a[0]); p[1] = f2bf(a[1]); p[2] = f2bf(a[2]); p[3] = f2bf(a[3]);
  p[4] = f2bf(b[0]); p[5] = f2bf(b[1]); p[6] = f2bf(b[2]); p[7] = f2bf(b[3]);
  *(u16x8*)(dst + i) = p;
}

// ---------------------------------------------------------------------------
// Kernel 2: 128x128-tile bf16 MFMA GEMM, C = relu(A @ Wt^T + bias) * outscale
//   Both operands staged via global_load_lds (16B), LDS XOR-swizzled (T2):
//   slot (row,c) holds data (row, c^(row&7)) via pre-swizzled SOURCE address.
//   OUT_MODE: 0 = fp32 row-major, 1 = bf16 row-major,
//             2 = bf16 transposed VpT[b][col][s] (fused V-transpose)
// ---------------------------------------------------------------------------
template <int OUT_MODE>
DEV void gemm_body(const unsigned short* __restrict__ A,
                   const unsigned short* __restrict__ Bt,
                   const float* __restrict__ bias, void* __restrict__ C_,
                   int m0, int n0, float outscale) {
  constexpr int Kd = 1024, Nd = 1024;
  __shared__ unsigned short Asl[128 * 64] __attribute__((aligned(16)));
  __shared__ unsigned short Bsl[128 * 64] __attribute__((aligned(16)));
  const int t = threadIdx.x, lane = t & 63, wave = t >> 6;
  const int grp = lane >> 4, r16 = lane & 15;
  const int wm = wave >> 1, wn = wave & 1;
  const int swz = (r16 & 7) << 4;  // read-side XOR (row&7 == r16&7 here)
  f32x4 acc[4][4] = {};
  for (int kt = 0; kt < Kd; kt += 64) {
#pragma unroll
    for (int j = 0; j < 4; ++j) {
      int chunk = (wave * 4 + j) * 64 + lane;
      int row = chunk >> 3, c = chunk & 7;
      int csw = c ^ (row & 7);
      gld16(Bt + (size_t)(n0 + row) * Kd + kt + csw * 8,
            (char*)Bsl + (wave * 4 + j) * 1024);
      gld16(A + (size_t)(m0 + row) * Kd + kt + csw * 8,
            (char*)Asl + (wave * 4 + j) * 1024);
    }
    __syncthreads();
#pragma unroll
    for (int cs = 0; cs < 2; ++cs) {
      b16x8 af[4], bfr[4];
#pragma unroll
      for (int mi = 0; mi < 4; ++mi)
        af[mi] = *(const b16x8*)((char*)Asl + (wm * 64 + mi * 16 + r16) * 128 +
                                 ((cs * 64 + grp * 16) ^ swz));
#pragma unroll
      for (int ni = 0; ni < 4; ++ni)
        bfr[ni] = *(const b16x8*)((char*)Bsl + (wn * 64 + ni * 16 + r16) * 128 +
                                  ((cs * 64 + grp * 16) ^ swz));
#pragma unroll
      for (int mi = 0; mi < 4; ++mi)
#pragma unroll
        for (int ni = 0; ni < 4; ++ni)
          acc[mi][ni] = __builtin_amdgcn_mfma_f32_16x16x32_bf16(
              af[mi], bfr[ni], acc[mi][ni], 0, 0, 0);
    }
    __syncthreads();
  }
  // epilogue: bias + relu (+scale); C/D layout: col=lane&15, row=(lane>>4)*4+r
#pragma unroll
  for (int mi = 0; mi < 4; ++mi) {
#pragma unroll
    for (int ni = 0; ni < 4; ++ni) {
      int col = n0 + wn * 64 + ni * 16 + r16;
      float bv = bias[col];
      int row0 = m0 + wm * 64 + mi * 16 + grp * 4;
      if constexpr (OUT_MODE == 2) {
        // VpT[b][col][s], 4 consecutive s per thread -> packed 8B store
        int bb = row0 >> 10, s = row0 & 1023;
        u16x4 pk;
#pragma unroll
        for (int r = 0; r < 4; ++r)
          pk[r] = f2bf(fmaxf(acc[mi][ni][r] + bv, 0.0f) * outscale);
        *(u16x4*)((unsigned short*)C_ +
                  (((size_t)(bb * 1024 + col)) << 10) + s) = pk;
      } else {
#pragma unroll
        for (int r = 0; r < 4; ++r) {
          float v = fmaxf(acc[mi][ni][r] + bv, 0.0f) * outscale;
          if constexpr (OUT_MODE == 1)
            ((unsigned short*)C_)[(size_t)(row0 + r) * Nd + col] = f2bf(v);
          else
            ((float*)C_)[(size_t)(row0 + r) * Nd + col] = v;
        }
      }
    }
  }
}

// Q projection pre-scaled by 1/sqrt(D)*log2(e) so attention softmax runs in
// exp2 domain with no per-score scaling (relu commutes with positive scale).
static constexpr float QSCALE = 0.03125f * 1.4426950408889634f;

// grid: 512 blocks, 1D; XCD-swizzled so the 8 n-tiles sharing an A-panel
// (and the whole 2 MB weight) land on one XCD's L2.
template <int OUT_MODE>
__global__ __launch_bounds__(256) void projz_kernel(
    const unsigned short* __restrict__ A, const unsigned short* __restrict__ Wt,
    const float* __restrict__ bias, void* __restrict__ dst, float outscale) {
  const int bid = blockIdx.x;                 // 512 = 8 xcd * 64
  const int id2 = (bid & 7) * 64 + (bid >> 3);
  const int n0 = (id2 & 7) * 128, m0 = (id2 >> 3) * 128;
  gemm_body<OUT_MODE>(A, Wt, bias, dst, m0, n0, outscale);
}

// ---------------------------------------------------------------------------
// Kernel 4: flash attention, swapped-QK^T, NO max tracking (post-ReLU Q,K>=0
// bounds scores; p=exp2(s) is overflow/underflow-safe; softmax shift-invar.).
// 8 waves x 128 q-rows per block: K/V staged once per 128 rows; LDS 48KB ->
// 3 blocks/CU = 24 waves/CU (TLP to hide the per-wave serial chain).
// l accumulated on the MFMA pipe via ones-column.
// ---------------------------------------------------------------------------
__global__ __launch_bounds__(512) void attn_kernel(
    const unsigned short* __restrict__ Qp, const unsigned short* __restrict__ Kp,
    const unsigned short* __restrict__ VpT, unsigned short* __restrict__ AO) {
  __shared__ unsigned short Ks[2][64 * 64] __attribute__((aligned(16)));
  __shared__ unsigned short Vs[2][64 * 64] __attribute__((aligned(16)));
  __shared__ unsigned short Ps[8 * 16 * 64] __attribute__((aligned(16)));
  const int t = threadIdx.x, lane = t & 63, wave = t >> 6;
  const int grp = lane >> 4, r16 = lane & 15;
  // XCD swizzle: 1024 blocks = 8 xcd * 128; each XCD owns 16 complete (b,h)
  // pairs (8 q-tiles each) -> K/V head-slices stay in that XCD's L2.
  const int bid = blockIdx.x;
  const int id2 = (bid & 7) * 128 + (bid >> 3);
  const int q0 = (id2 & 7) * 128;
  const int bh = id2 >> 3;
  const int b = bh & 7, head = bh >> 3;

  // staging: 512 threads cover K tile (512 x 16B) and V tile each 1:1
  const int srow = t >> 3, scc = t & 7;
  const int csw = scc ^ (srow & 7);
  const unsigned short* kbase = Kp + ((size_t)b * Ssz) * Dsz + head * 64;
  const unsigned short* vbase = VpT + ((size_t)b * Dsz + head * 64) * Ssz;

  // Q fragments (B-operand layout: row=lane&15 ↔ q, k = 8*grp + j)
  const int sq = q0 + wave * 16 + r16;
  const unsigned short* qbase = Qp + ((size_t)b * Ssz + sq) * Dsz + head * 64;
  b16x8 qf0 = *(const b16x8*)(qbase + grp * 8);
  b16x8 qf1 = *(const b16x8*)(qbase + 32 + grp * 8);

  f32x4 o[4] = {};
  f32x4 o_l = {};  // l accumulated by the MFMA pipe (ones-column)
  const f32x4 zero4 = {0.0f, 0.0f, 0.0f, 0.0f};
  const b16x8 ones = {16256, 16256, 16256, 16256,
                      16256, 16256, 16256, 16256};  // bf16 1.0 x8

  auto stage = [&](int kv0, int pb) {
    gld16(kbase + (size_t)(kv0 + srow) * Dsz + csw * 8,
          (char*)Ks[pb] + wave * 1024);
    gld16(vbase + (size_t)srow * Ssz + kv0 + csw * 8,
          (char*)Vs[pb] + wave * 1024);
  };

  stage(0, 0);
  __syncthreads();
  int cur = 0;

  for (int it = 0; it < 16; ++it) {
    if (it < 15) stage((it + 1) * 64, cur ^ 1);  // issue-early: overlaps compute

    // S^T = K Q^T : sc[f] rows = k = f*16 + grp*4 + r, col = q = r16
    __builtin_amdgcn_s_setprio(1);
    f32x4 sc[4];
#pragma unroll
    for (int f = 0; f < 4; ++f) {
      int k = f * 16 + r16;
      int kswz = (k & 7) << 4;
      const char* kb = (const char*)Ks[cur] + k * 128;
      b16x8 kf0 = *(const b16x8*)(kb + ((grp * 16) ^ kswz));
      b16x8 kf1 = *(const b16x8*)(kb + ((64 + grp * 16) ^ kswz));
      f32x4 s = __builtin_amdgcn_mfma_f32_16x16x32_bf16(kf0, qf0, zero4, 0, 0, 0);
      sc[f] = __builtin_amdgcn_mfma_f32_16x16x32_bf16(kf1, qf1, s, 0, 0, 0);
    }
    __builtin_amdgcn_s_setprio(0);

    // p = exp2(s); pack P row q=r16: 4x 8B writes via v_cvt_pk_bf16_f32
    {
      char* prow = (char*)Ps + wave * 2048 + r16 * 128;
      int qs = (r16 & 7) << 4;
#pragma unroll
      for (int f = 0; f < 4; ++f) {
        u32x2 w;
        w[0] = cvt2(exp2f(sc[f][0]), exp2f(sc[f][1]));
        w[1] = cvt2(exp2f(sc[f][2]), exp2f(sc[f][3]));
        *(u32x2*)(prow + ((f * 32 + grp * 8) ^ qs)) = w;
      }
    }

    // O += P V ; l += P 1 (ones-column on the MFMA pipe)
    __builtin_amdgcn_s_setprio(1);
#pragma unroll
    for (int ks = 0; ks < 2; ++ks) {
      int pswz = (r16 & 7) << 4;
      b16x8 pa = *(const b16x8*)((char*)Ps + wave * 2048 + r16 * 128 +
                                 ((ks * 64 + grp * 16) ^ pswz));
      o_l = __builtin_amdgcn_mfma_f32_16x16x32_bf16(pa, ones, o_l, 0, 0, 0);
#pragma unroll
      for (int fc = 0; fc < 4; ++fc) {
        int d = fc * 16 + r16;
        int vswz = (d & 7) << 4;
        b16x8 vb = *(const b16x8*)((char*)Vs[cur] + d * 128 +
                                   ((ks * 64 + grp * 16) ^ vswz));
        o[fc] = __builtin_amdgcn_mfma_f32_16x16x32_bf16(pa, vb, o[fc], 0, 0, 0);
      }
    }
    __builtin_amdgcn_s_setprio(0);
    __syncthreads();  // drains next-tile vmcnt after compute; read-fence for swap
    cur ^= 1;
  }

  // O /= l ; o and o_l share the D-layout (row q = grp*4+r) -> no broadcast
#pragma unroll
  for (int fc = 0; fc < 4; ++fc) {
    int col = head * 64 + fc * 16 + r16;
#pragma unroll
    for (int r = 0; r < 4; ++r) {
      int row = q0 + wave * 16 + grp * 4 + r;
      AO[((size_t)b * Ssz + row) * Dsz + col] = f2bf(o[fc][r] / o_l[r]);
    }
  }
}

// ---------------------------------------------------------------------------
extern "C" void kernel_launch(void* const* d_in, const int* in_sizes, int n_in,
                              void* d_out, int out_size, void* d_ws,
                              size_t ws_size, hipStream_t stream) {
  const float* Q = (const float*)d_in[0];
  const float* K = (const float*)d_in[1];
  const float* V = (const float*)d_in[2];
  const float* WQ = (const float*)d_in[3];
  const float* bQ = (const float*)d_in[4];
  const float* WK = (const float*)d_in[5];
  const float* bK = (const float*)d_in[6];
  const float* WV = (const float*)d_in[7];
  const float* bV = (const float*)d_in[8];
  const float* WO = (const float*)d_in[9];
  const float* bO = (const float*)d_in[10];

  char* ws = (char*)d_ws;
  const size_t MB = 1024ull * 1024ull;
  const size_t DD = (size_t)Dsz * Dsz;
  unsigned short* Wt = (unsigned short*)(ws);             // 8 MB: 4x[n][k] bf16
  unsigned short* Cbf = (unsigned short*)(ws + 8 * MB);   // 16 MB convert buf
  unsigned short* Qp = (unsigned short*)(ws + 24 * MB);   // 16 MB
  unsigned short* Kp = (unsigned short*)(ws + 40 * MB);   // 16 MB
  unsigned short* VpT = (unsigned short*)(ws + 56 * MB);  // 16 MB
  unsigned short* AO = Cbf;  // convert buf dead after last proj -> reuse

  wconv_kernel<<<dim3(16, 16, 4), 256, 0, stream>>>(WQ, WK, WV, WO, Wt);
  // per-z: convert input to bf16, then pure-gld16 GEMM (stream serializes)
  conv_kernel<<<4096, 256, 0, stream>>>(Q, Cbf);
  projz_kernel<1><<<512, 256, 0, stream>>>(Cbf, Wt, bQ, Qp, QSCALE);
  conv_kernel<<<4096, 256, 0, stream>>>(K, Cbf);
  projz_kernel<1><<<512, 256, 0, stream>>>(Cbf, Wt + DD, bK, Kp, 1.0f);
  conv_kernel<<<4096, 256, 0, stream>>>(V, Cbf);
  projz_kernel<2><<<512, 256, 0, stream>>>(Cbf, Wt + 2 * DD, bV, VpT, 1.0f);
  attn_kernel<<<1024, 512, 0, stream>>>(Qp, Kp, VpT, AO);
  projz_kernel<0><<<512, 256, 0, stream>>>(AO, Wt + 3 * DD, bO, (float*)d_out,
                                           1.0f);
}

// Round 8
// 173.997 us; speedup vs baseline: 1.6876x; 1.1454x over previous
//
#include <hip/hip_runtime.h>
#include <hip/hip_bf16.h>
#include <cstdint>

#define DEV __device__ __forceinline__

typedef __attribute__((ext_vector_type(4))) float f32x4;
typedef __attribute__((ext_vector_type(8))) short b16x8;
typedef __attribute__((ext_vector_type(4))) unsigned short u16x4;
typedef __attribute__((ext_vector_type(8))) unsigned short u16x8;
typedef __attribute__((ext_vector_type(2))) unsigned int u32x2;

typedef __attribute__((address_space(1))) void gvoid_t;
typedef __attribute__((address_space(3))) void lvoid_t;

static constexpr int Bsz = 8, Ssz = 1024, Dsz = 1024;
static constexpr int Mrows = Bsz * Ssz;  // 8192

// async global->LDS, 16B per lane; lds base must be wave-uniform (HW adds lane*16)
DEV void gld16(const void* g, void* l) {
  __builtin_amdgcn_global_load_lds((gvoid_t*)(uintptr_t)g,
                                   (lvoid_t*)(unsigned)(uintptr_t)l, 16, 0, 0);
}

// fp32 -> bf16 RNE (finite inputs only) — cold paths only
DEV unsigned short f2bf(float x) {
  unsigned int u = __float_as_uint(x);
  u += 0x7fffu + ((u >> 16) & 1u);
  return (unsigned short)(u >> 16);
}

// hot path: paired convert -> v_cvt_pk_bf16_f32
DEV unsigned int cvt2(float lo, float hi) {
  __hip_bfloat162 h = __float22bfloat162_rn(make_float2(lo, hi));
  unsigned int u;
  __builtin_memcpy(&u, &h, 4);
  return u;
}

// ---------------------------------------------------------------------------
// Kernel 1: convert+transpose 4 weight matrices: Wt[w][n][k] = bf16(W[k][n])
// ---------------------------------------------------------------------------
__global__ __launch_bounds__(256) void wconv_kernel(
    const float* __restrict__ WQ, const float* __restrict__ WK,
    const float* __restrict__ WV, const float* __restrict__ WO,
    unsigned short* __restrict__ Wt) {
  __shared__ float tile[64][65];
  const int w = blockIdx.z;
  const float* W = (w == 0) ? WQ : (w == 1) ? WK : (w == 2) ? WV : WO;
  const int k0 = blockIdx.x * 64, n0 = blockIdx.y * 64;
  const int t = threadIdx.x;
  {
    const int r = t >> 4;
    const int c = (t & 15) * 4;
#pragma unroll
    for (int i = 0; i < 4; ++i) {
      f32x4 v = *(const f32x4*)(W + (size_t)(k0 + i * 16 + r) * Dsz + n0 + c);
      tile[i * 16 + r][c + 0] = v[0];
      tile[i * 16 + r][c + 1] = v[1];
      tile[i * 16 + r][c + 2] = v[2];
      tile[i * 16 + r][c + 3] = v[3];
    }
  }
  __syncthreads();
  {
    const int n = t >> 2;
    const int ks = (t & 3) * 16;
    unsigned short* dst =
        Wt + (size_t)w * Dsz * Dsz + (size_t)(n0 + n) * Dsz + k0 + ks;
#pragma unroll
    for (int j = 0; j < 16; j += 4) {
      u16x4 p;
#pragma unroll
      for (int jj = 0; jj < 4; ++jj) p[jj] = f2bf(tile[ks + j + jj][n]);
      *(u16x4*)(dst + j) = p;
    }
  }
}

// ---------------------------------------------------------------------------
// Kernel 2: 128x128-tile bf16 MFMA GEMM, C = relu(A @ Wt^T + bias) * outscale
//   B staged via global_load_lds (16B). A: if A_FP32, reg-staged fp32 with
//   in-flight cvt_pk -> bf16 LDS (kills the separate convert pass); else
//   bf16 via global_load_lds. LDS XOR-swizzled (T2): slot (row,c) holds data
//   (row, c^(row&7)); gld16 paths pre-swizzle the SOURCE address, the
//   reg-staged path reads swizzled source and writes linear slots.
//   OUT_MODE: 0 = fp32 row-major, 1 = bf16 row-major,
//             2 = bf16 transposed VpT[b][col][s] (fused V-transpose)
// ---------------------------------------------------------------------------
template <bool A_FP32, int OUT_MODE>
DEV void gemm_body(const void* __restrict__ A_,
                   const unsigned short* __restrict__ Bt,
                   const float* __restrict__ bias, void* __restrict__ C_,
                   int m0, int n0, float outscale) {
  constexpr int Kd = 1024, Nd = 1024;
  __shared__ unsigned short Asl[128 * 64] __attribute__((aligned(16)));
  __shared__ unsigned short Bsl[128 * 64] __attribute__((aligned(16)));
  const int t = threadIdx.x, lane = t & 63, wave = t >> 6;
  const int grp = lane >> 4, r16 = lane & 15;
  const int wm = wave >> 1, wn = wave & 1;
  const int swz = (r16 & 7) << 4;  // read-side XOR (row&7 == r16&7 here)
  f32x4 acc[4][4] = {};
  for (int kt = 0; kt < Kd; kt += 64) {
#pragma unroll
    for (int j = 0; j < 4; ++j) {
      int chunk = (wave * 4 + j) * 64 + lane;
      int row = chunk >> 3, c = chunk & 7;
      int csw = c ^ (row & 7);
      gld16(Bt + (size_t)(n0 + row) * Kd + kt + csw * 8,
            (char*)Bsl + (wave * 4 + j) * 1024);
      if constexpr (!A_FP32) {
        gld16((const unsigned short*)A_ + (size_t)(m0 + row) * Kd + kt + csw * 8,
              (char*)Asl + (wave * 4 + j) * 1024);
      }
    }
    if constexpr (A_FP32) {
      const float* A = (const float*)A_;
#pragma unroll
      for (int it = 0; it < 4; ++it) {
        int chunk = it * 256 + t;
        int row = chunk >> 3, c = chunk & 7;
        int csw = c ^ (row & 7);
        const float* src = A + (size_t)(m0 + row) * Kd + kt + csw * 8;
        f32x4 v0 = *(const f32x4*)src;
        f32x4 v1 = *(const f32x4*)(src + 4);
        u32x2 w0, w1;
        w0[0] = cvt2(v0[0], v0[1]);
        w0[1] = cvt2(v0[2], v0[3]);
        w1[0] = cvt2(v1[0], v1[1]);
        w1[1] = cvt2(v1[2], v1[3]);
        *(u32x2*)((char*)Asl + chunk * 16) = w0;
        *(u32x2*)((char*)Asl + chunk * 16 + 8) = w1;
      }
    }
    __syncthreads();
#pragma unroll
    for (int cs = 0; cs < 2; ++cs) {
      b16x8 af[4], bfr[4];
#pragma unroll
      for (int mi = 0; mi < 4; ++mi)
        af[mi] = *(const b16x8*)((char*)Asl + (wm * 64 + mi * 16 + r16) * 128 +
                                 ((cs * 64 + grp * 16) ^ swz));
#pragma unroll
      for (int ni = 0; ni < 4; ++ni)
        bfr[ni] = *(const b16x8*)((char*)Bsl + (wn * 64 + ni * 16 + r16) * 128 +
                                  ((cs * 64 + grp * 16) ^ swz));
#pragma unroll
      for (int mi = 0; mi < 4; ++mi)
#pragma unroll
        for (int ni = 0; ni < 4; ++ni)
          acc[mi][ni] = __builtin_amdgcn_mfma_f32_16x16x32_bf16(
              af[mi], bfr[ni], acc[mi][ni], 0, 0, 0);
    }
    __syncthreads();
  }
  // epilogue: bias + relu (+scale); C/D layout: col=lane&15, row=(lane>>4)*4+r
#pragma unroll
  for (int mi = 0; mi < 4; ++mi) {
#pragma unroll
    for (int ni = 0; ni < 4; ++ni) {
      int col = n0 + wn * 64 + ni * 16 + r16;
      float bv = bias[col];
      int row0 = m0 + wm * 64 + mi * 16 + grp * 4;
      if constexpr (OUT_MODE == 2) {
        // VpT[b][col][s], 4 consecutive s per thread -> packed 8B store
        int bb = row0 >> 10, s = row0 & 1023;
        u16x4 pk;
#pragma unroll
        for (int r = 0; r < 4; ++r)
          pk[r] = f2bf(fmaxf(acc[mi][ni][r] + bv, 0.0f) * outscale);
        *(u16x4*)((unsigned short*)C_ +
                  (((size_t)(bb * 1024 + col)) << 10) + s) = pk;
      } else {
#pragma unroll
        for (int r = 0; r < 4; ++r) {
          float v = fmaxf(acc[mi][ni][r] + bv, 0.0f) * outscale;
          if constexpr (OUT_MODE == 1)
            ((unsigned short*)C_)[(size_t)(row0 + r) * Nd + col] = f2bf(v);
          else
            ((float*)C_)[(size_t)(row0 + r) * Nd + col] = v;
        }
      }
    }
  }
}

// Q projection pre-scaled by 1/sqrt(D)*log2(e) so attention softmax runs in
// exp2 domain with no per-score scaling (relu commutes with positive scale).
static constexpr float QSCALE = 0.03125f * 1.4426950408889634f;

// Q/K/V projections in ONE launch (z = which); reads fp32 inputs directly.
// x-grid 512 = 8 xcd * 64, XCD-swizzled: the 8 n-tiles sharing an A-panel
// (and the whole 2 MB weight) land on one XCD's L2.
__global__ __launch_bounds__(256) void proj3_kernel(
    const float* __restrict__ Q, const float* __restrict__ K,
    const float* __restrict__ V, const unsigned short* __restrict__ Wt,
    const float* __restrict__ bQ, const float* __restrict__ bK,
    const float* __restrict__ bV, unsigned short* __restrict__ Qp,
    unsigned short* __restrict__ Kp, unsigned short* __restrict__ VpT) {
  const size_t DD = (size_t)Dsz * Dsz;
  const int bid = blockIdx.x;  // 512 = 8 xcd * 64
  const int id2 = (bid & 7) * 64 + (bid >> 3);
  const int n0 = (id2 & 7) * 128, m0 = (id2 >> 3) * 128;
  const int z = blockIdx.z;
  if (z == 0)
    gemm_body<true, 1>(Q, Wt, bQ, Qp, m0, n0, QSCALE);
  else if (z == 1)
    gemm_body<true, 1>(K, Wt + DD, bK, Kp, m0, n0, 1.0f);
  else
    gemm_body<true, 2>(V, Wt + 2 * DD, bV, VpT, m0, n0, 1.0f);
}

__global__ __launch_bounds__(256) void out_gemm_kernel(
    const unsigned short* __restrict__ AO,
    const unsigned short* __restrict__ WOt, const float* __restrict__ bO,
    float* __restrict__ Out) {
  const int bid = blockIdx.x;
  const int id2 = (bid & 7) * 64 + (bid >> 3);
  const int n0 = (id2 & 7) * 128, m0 = (id2 >> 3) * 128;
  gemm_body<false, 0>(AO, WOt, bO, Out, m0, n0, 1.0f);
}

// ---------------------------------------------------------------------------
// Kernel 4: flash attention, swapped-QK^T, NO max tracking (post-ReLU Q,K>=0
// bounds scores; p=exp2(s) is overflow/underflow-safe; softmax shift-invar.).
// 8 waves x 2 q-subtiles x 16 rows = 256 q-rows per block; K/V fragments and
// staging shared across both subtiles (halves ds_read + staging + barriers
// per unit work, doubles per-wave ILP: subtile-B MFMAs overlap subtile-A exp).
// grid 512 = exactly 2 blocks/CU (LDS 64KB). l via ones-column on MFMA pipe.
// ---------------------------------------------------------------------------
__global__ __launch_bounds__(512, 4) void attn_kernel(
    const unsigned short* __restrict__ Qp, const unsigned short* __restrict__ Kp,
    const unsigned short* __restrict__ VpT, unsigned short* __restrict__ AO) {
  __shared__ unsigned short Ks[2][64 * 64] __attribute__((aligned(16)));
  __shared__ unsigned short Vs[2][64 * 64] __attribute__((aligned(16)));
  __shared__ unsigned short Ps[16][16 * 64] __attribute__((aligned(16)));
  const int t = threadIdx.x, lane = t & 63, wave = t >> 6;
  const int grp = lane >> 4, r16 = lane & 15;
  // XCD swizzle: 512 blocks = 8 xcd * 64; each XCD owns 16 complete (b,h)
  // pairs (4 q-tiles each) -> K/V head-slices stay in that XCD's L2.
  const int bid = blockIdx.x;
  const int id2 = (bid & 7) * 64 + (bid >> 3);
  const int q0 = (id2 & 3) * 256;
  const int bh = id2 >> 2;
  const int b = bh & 7, head = bh >> 3;

  // staging: 512 threads cover K tile (512 x 16B) and V tile each 1:1
  const int srow = t >> 3, scc = t & 7;
  const int csw = scc ^ (srow & 7);
  const unsigned short* kbase = Kp + ((size_t)b * Ssz) * Dsz + head * 64;
  const unsigned short* vbase = VpT + ((size_t)b * Dsz + head * 64) * Ssz;

  // Q fragments for both subtiles (B-operand layout: row=lane&15, k=8*grp+j)
  const int sqA = q0 + wave * 16 + r16;
  const unsigned short* qbA = Qp + ((size_t)b * Ssz + sqA) * Dsz + head * 64;
  const unsigned short* qbB = qbA + (size_t)128 * Dsz;
  b16x8 qfA0 = *(const b16x8*)(qbA + grp * 8);
  b16x8 qfA1 = *(const b16x8*)(qbA + 32 + grp * 8);
  b16x8 qfB0 = *(const b16x8*)(qbB + grp * 8);
  b16x8 qfB1 = *(const b16x8*)(qbB + 32 + grp * 8);

  f32x4 oA[4] = {}, oB[4] = {};
  f32x4 olA = {}, olB = {};
  const f32x4 zero4 = {0.0f, 0.0f, 0.0f, 0.0f};
  const b16x8 ones = {16256, 16256, 16256, 16256,
                      16256, 16256, 16256, 16256};  // bf16 1.0 x8

  auto stage = [&](int kv0, int pb) {
    gld16(kbase + (size_t)(kv0 + srow) * Dsz + csw * 8,
          (char*)Ks[pb] + wave * 1024);
    gld16(vbase + (size_t)srow * Ssz + kv0 + csw * 8,
          (char*)Vs[pb] + wave * 1024);
  };

  stage(0, 0);
  __syncthreads();
  int cur = 0;

  for (int it = 0; it < 16; ++it) {
    if (it < 15) stage((it + 1) * 64, cur ^ 1);  // issue-early: overlaps compute

    // S^T = K Q^T for both subtiles, sharing the K fragment loads.
    // sc*[f] rows = k = f*16 + grp*4 + r, col = q = r16
    __builtin_amdgcn_s_setprio(1);
    f32x4 scA[4], scB[4];
#pragma unroll
    for (int f = 0; f < 4; ++f) {
      int k = f * 16 + r16;
      int kswz = (k & 7) << 4;
      const char* kb = (const char*)Ks[cur] + k * 128;
      b16x8 kf0 = *(const b16x8*)(kb + ((grp * 16) ^ kswz));
      b16x8 kf1 = *(const b16x8*)(kb + ((64 + grp * 16) ^ kswz));
      f32x4 sA = __builtin_amdgcn_mfma_f32_16x16x32_bf16(kf0, qfA0, zero4, 0, 0, 0);
      scA[f] = __builtin_amdgcn_mfma_f32_16x16x32_bf16(kf1, qfA1, sA, 0, 0, 0);
      f32x4 sB = __builtin_amdgcn_mfma_f32_16x16x32_bf16(kf0, qfB0, zero4, 0, 0, 0);
      scB[f] = __builtin_amdgcn_mfma_f32_16x16x32_bf16(kf1, qfB1, sB, 0, 0, 0);
    }
    __builtin_amdgcn_s_setprio(0);

    // p = exp2(s); pack P rows (q=r16) for both subtiles: 8B writes via cvt_pk
    {
      int qs = (r16 & 7) << 4;
      char* prowA = (char*)Ps + (wave * 2 + 0) * 2048 + r16 * 128;
      char* prowB = (char*)Ps + (wave * 2 + 1) * 2048 + r16 * 128;
#pragma unroll
      for (int f = 0; f < 4; ++f) {
        u32x2 w;
        w[0] = cvt2(exp2f(scA[f][0]), exp2f(scA[f][1]));
        w[1] = cvt2(exp2f(scA[f][2]), exp2f(scA[f][3]));
        *(u32x2*)(prowA + ((f * 32 + grp * 8) ^ qs)) = w;
      }
#pragma unroll
      for (int f = 0; f < 4; ++f) {
        u32x2 w;
        w[0] = cvt2(exp2f(scB[f][0]), exp2f(scB[f][1]));
        w[1] = cvt2(exp2f(scB[f][2]), exp2f(scB[f][3]));
        *(u32x2*)(prowB + ((f * 32 + grp * 8) ^ qs)) = w;
      }
    }

    // O += P V ; l += P 1 — V fragments shared across subtiles
    __builtin_amdgcn_s_setprio(1);
#pragma unroll
    for (int ks = 0; ks < 2; ++ks) {
      int pswz = (r16 & 7) << 4;
      int poff = r16 * 128 + ((ks * 64 + grp * 16) ^ pswz);
      b16x8 paA = *(const b16x8*)((char*)Ps + (wave * 2 + 0) * 2048 + poff);
      b16x8 paB = *(const b16x8*)((char*)Ps + (wave * 2 + 1) * 2048 + poff);
      olA = __builtin_amdgcn_mfma_f32_16x16x32_bf16(paA, ones, olA, 0, 0, 0);
      olB = __builtin_amdgcn_mfma_f32_16x16x32_bf16(paB, ones, olB, 0, 0, 0);
#pragma unroll
      for (int fc = 0; fc < 4; ++fc) {
        int d = fc * 16 + r16;
        int vswz = (d & 7) << 4;
        b16x8 vb = *(const b16x8*)((char*)Vs[cur] + d * 128 +
                                   ((ks * 64 + grp * 16) ^ vswz));
        oA[fc] = __builtin_amdgcn_mfma_f32_16x16x32_bf16(paA, vb, oA[fc], 0, 0, 0);
        oB[fc] = __builtin_amdgcn_mfma_f32_16x16x32_bf16(paB, vb, oB[fc], 0, 0, 0);
      }
    }
    __builtin_amdgcn_s_setprio(0);
    __syncthreads();  // drains next-tile vmcnt after compute; read-fence for swap
    cur ^= 1;
  }

  // O /= l ; o and ol share the D-layout (row q = grp*4+r) -> no broadcast
#pragma unroll
  for (int fc = 0; fc < 4; ++fc) {
    int col = head * 64 + fc * 16 + r16;
#pragma unroll
    for (int r = 0; r < 4; ++r) {
      int rowA = q0 + wave * 16 + grp * 4 + r;
      AO[((size_t)b * Ssz + rowA) * Dsz + col] = f2bf(oA[fc][r] / olA[r]);
      AO[((size_t)b * Ssz + rowA + 128) * Dsz + col] = f2bf(oB[fc][r] / olB[r]);
    }
  }
}

// ---------------------------------------------------------------------------
extern "C" void kernel_launch(void* const* d_in, const int* in_sizes, int n_in,
                              void* d_out, int out_size, void* d_ws,
                              size_t ws_size, hipStream_t stream) {
  const float* Q = (const float*)d_in[0];
  const float* K = (const float*)d_in[1];
  const float* V = (const float*)d_in[2];
  const float* WQ = (const float*)d_in[3];
  const float* bQ = (const float*)d_in[4];
  const float* WK = (const float*)d_in[5];
  const float* bK = (const float*)d_in[6];
  const float* WV = (const float*)d_in[7];
  const float* bV = (const float*)d_in[8];
  const float* WO = (const float*)d_in[9];
  const float* bO = (const float*)d_in[10];

  char* ws = (char*)d_ws;
  const size_t MB = 1024ull * 1024ull;
  const size_t DD = (size_t)Dsz * Dsz;
  unsigned short* Wt = (unsigned short*)(ws);             // 8 MB: 4x[n][k] bf16
  unsigned short* Qp = (unsigned short*)(ws + 8 * MB);    // 16 MB
  unsigned short* Kp = (unsigned short*)(ws + 24 * MB);   // 16 MB
  unsigned short* VpT = (unsigned short*)(ws + 40 * MB);  // 16 MB
  unsigned short* AO = (unsigned short*)(ws + 56 * MB);   // 16 MB

  wconv_kernel<<<dim3(16, 16, 4), 256, 0, stream>>>(WQ, WK, WV, WO, Wt);
  proj3_kernel<<<dim3(512, 1, 3), 256, 0, stream>>>(Q, K, V, Wt, bQ, bK, bV,
                                                    Qp, Kp, VpT);
  attn_kernel<<<512, 512, 0, stream>>>(Qp, Kp, VpT, AO);
  out_gemm_kernel<<<512, 256, 0, stream>>>(AO, Wt + 3 * DD, bO, (float*)d_out);
}